// Round 9
// baseline (288.399 us; speedup 1.0000x reference)
//
#include <hip/hip_runtime.h>
#include <hip/hip_fp16.h>
#include <cstdint>
#include <cstddef>

// Problem constants (match reference)
#define Bn 4
#define Nn 2048
#define Dn 128
#define OUTn 64
#define Sn 8          // 4 batches x {fwd, rev}
#define MAXDEG 128    // binomial(2048, 1/32): mean 64, sd 7.9; max over 16K rows ~99
#define NITER 3

// ---------------------------------------------------------------------------
// deposit low 16 bits of x at bit positions 0,4,8,...,60
__device__ __forceinline__ unsigned long long spread4(unsigned long long x) {
    x &= 0xFFFFull;
    x = (x | (x << 24)) & 0x000000FF000000FFull;
    x = (x | (x << 12)) & 0x000F000F000F000Full;
    x = (x | (x << 6))  & 0x0303030303030303ull;
    x = (x | (x << 3))  & 0x1111111111111111ull;
    return x;
}

// ---------------------------------------------------------------------------
// Blocks [0, 4096): one wave per forward row (b,i): forward adjacency
// (sorted, deterministic), degree, and the column-major bitmask.
// Blocks [4096, 5120): row-organized init: x[s]=relu(INPUT[b]) for s=b,b+4
// AND the iteration-0 attention scalars ah1/ah2 (32-lane shfl reduce).
__global__ void fwd_bits_init(const float4* __restrict__ cfg4,
                              unsigned long long* __restrict__ bits,
                              int* __restrict__ adj, int* __restrict__ deg,
                              const float4* __restrict__ in4, float4* __restrict__ x4,
                              const float* __restrict__ w1, const float* __restrict__ b1,
                              const float* __restrict__ w2, const float* __restrict__ b2,
                              float* __restrict__ ah1, float* __restrict__ ah2) {
    if (blockIdx.x >= (Bn * Nn) / 4) {
        int blk = blockIdx.x - (Bn * Nn) / 4;         // 0..1023
        int t = threadIdx.x;
        int row = blk * 8 + (t >> 5);                 // [0, Bn*Nn)
        int q   = t & 31;                             // feature quad
        float4 v = in4[(size_t)row * 32 + q];
        v.x = v.x > 0.f ? v.x : 0.f;
        v.y = v.y > 0.f ? v.y : 0.f;
        v.z = v.z > 0.f ? v.z : 0.f;
        v.w = v.w > 0.f ? v.w : 0.f;
        x4[(size_t)row * 32 + q] = v;
        x4[(size_t)(Bn * Nn * Dn) / 4 + (size_t)row * 32 + q] = v;
        const float4* w14 = (const float4*)w1;
        const float4* w24 = (const float4*)w2;
        float4 wa = w14[q], wb = w24[q];
        float p1 = v.x * wa.x + v.y * wa.y + v.z * wa.z + v.w * wa.w;
        float p2 = v.x * wb.x + v.y * wb.y + v.z * wb.z + v.w * wb.w;
        #pragma unroll
        for (int o = 16; o >= 1; o >>= 1) {
            p1 += __shfl_xor(p1, o);
            p2 += __shfl_xor(p2, o);
        }
        if (q == 0) {
            float a1 = p1 + b1[0], a2 = p2 + b2[0];
            ah1[row] = a1; ah1[Bn * Nn + row] = a1;   // fwd slot b, rev slot 4+b
            ah2[row] = a2; ah2[Bn * Nn + row] = a2;
        }
        return;
    }
    int row  = blockIdx.x * 4 + (threadIdx.x >> 6);   // [0, Bn*Nn)
    int lane = threadIdx.x & 63;
    int b = row >> 11;
    int i = row & (Nn - 1);
    const float4* crow = cfg4 + (size_t)row * (Nn / 4);
    int* dst = adj + (size_t)row * MAXDEG;
    int cnt = 0;
    for (int j0 = 0; j0 < Nn; j0 += 256) {
        float4 v = crow[(j0 >> 2) + lane];
        int nib = (v.x != 0.f) | ((v.y != 0.f) << 1) |
                  ((v.z != 0.f) << 2) | ((v.w != 0.f) << 3);
        unsigned long long m0 = __ballot(nib & 1);
        unsigned long long m1 = __ballot(nib & 2);
        unsigned long long m2 = __ballot(nib & 4);
        unsigned long long m3 = __ballot(nib & 8);
        unsigned long long below = (1ull << lane) - 1ull;
        int off = __popcll(m0 & below) + __popcll(m1 & below) +
                  __popcll(m2 & below) + __popcll(m3 & below);
        int total = __popcll(m0) + __popcll(m1) + __popcll(m2) + __popcll(m3);
        int base = cnt + off;
        int col = j0 + 4 * lane;
        if (nib & 1) { if (base < MAXDEG) dst[base] = col;     base++; }
        if (nib & 2) { if (base < MAXDEG) dst[base] = col + 1; base++; }
        if (nib & 4) { if (base < MAXDEG) dst[base] = col + 2; base++; }
        if (nib & 8) { if (base < MAXDEG) dst[base] = col + 3; base++; }
        if (lane < 4) {
            int sh = lane << 4;
            unsigned long long w = spread4(m0 >> sh) | (spread4(m1 >> sh) << 1) |
                                   (spread4(m2 >> sh) << 2) | (spread4(m3 >> sh) << 3);
            int jw = (j0 >> 6) + lane;
            bits[((size_t)(b * 32 + jw)) * Nn + i] = w;
        }
        cnt += total;
    }
    if (lane == 0) deg[row] = (cnt < MAXDEG ? cnt : MAXDEG);
}

// ---------------------------------------------------------------------------
// One wave per reverse row (b,j): read plane bits[b][j>>6][*] contiguously;
// ballot-compact ascending i. Deterministic and sorted.
__global__ void rev_adj(const unsigned long long* __restrict__ bits,
                        int* __restrict__ adj, int* __restrict__ deg) {
    int r    = blockIdx.x * 4 + (threadIdx.x >> 6);   // [0, Bn*Nn)
    int lane = threadIdx.x & 63;
    int b = r >> 11;
    int j = r & (Nn - 1);
    const unsigned long long* col = bits + ((size_t)(b * 32 + (j >> 6))) * Nn;
    int bit = j & 63;
    int out_r = (Bn + b) * Nn + j;
    int* dst = adj + (size_t)out_r * MAXDEG;
    int cnt = 0;
    for (int i0 = 0; i0 < Nn; i0 += 64) {
        unsigned long long word = col[i0 + lane];
        bool e = (word >> bit) & 1;
        unsigned long long m = __ballot(e);
        if (e) {
            int pos = cnt + __popcll(m & ((1ull << lane) - 1ull));
            if (pos < MAXDEG) dst[pos] = i0 + lane;
        }
        cnt += __popcll(m);
    }
    if (lane == 0) deg[out_r] = (cnt < MAXDEG ? cnt : MAXDEG);
}

// ---------------------------------------------------------------------------
// Pure streaming GEMM: xw = fp16(x @ W). 8 rows per 128-thread block; x-row
// loads wave-uniform (scalar path), W loads coalesced + cache resident.
// No LDS, no barriers.
__global__ void gemm_xw(const float* __restrict__ x, const float* __restrict__ W,
                        __half* __restrict__ xwh) {
    int c = threadIdx.x;                              // column 0..127
    size_t rbase = (size_t)blockIdx.x * 8 * Dn;
    const float* x0 = x + rbase;
    float a0 = 0.f, a1 = 0.f, a2 = 0.f, a3 = 0.f;
    float a4 = 0.f, a5 = 0.f, a6 = 0.f, a7 = 0.f;
    #pragma unroll 4
    for (int k = 0; k < Dn; ++k) {
        float w = W[k * Dn + c];
        a0 = fmaf(x0[0 * Dn + k], w, a0);
        a1 = fmaf(x0[1 * Dn + k], w, a1);
        a2 = fmaf(x0[2 * Dn + k], w, a2);
        a3 = fmaf(x0[3 * Dn + k], w, a3);
        a4 = fmaf(x0[4 * Dn + k], w, a4);
        a5 = fmaf(x0[5 * Dn + k], w, a5);
        a6 = fmaf(x0[6 * Dn + k], w, a6);
        a7 = fmaf(x0[7 * Dn + k], w, a7);
    }
    xwh[rbase + 0 * Dn + c] = __float2half(a0);
    xwh[rbase + 1 * Dn + c] = __float2half(a1);
    xwh[rbase + 2 * Dn + c] = __float2half(a2);
    xwh[rbase + 3 * Dn + c] = __float2half(a3);
    xwh[rbase + 4 * Dn + c] = __float2half(a4);
    xwh[rbase + 5 * Dn + c] = __float2half(a5);
    xwh[rbase + 6 * Dn + c] = __float2half(a6);
    xwh[rbase + 7 * Dn + c] = __float2half(a7);
}

// ---------------------------------------------------------------------------
// Fused: masked softmax + sparse aggregate of fp16 xw + residual + ELU,
// updating x in place; epilogue computes next-iteration ah1/ah2 (double-
// buffered: reads ah*r, writes ah*w — avoids neighbor read/write race).
// ONE WAVE PER ROW, no barriers. Gather is software-pipelined: chunk k+1's
// (p,j) LDS reads + 4 xw loads are issued before chunk k's FMAs -> ~8 loads
// in flight per wave.
__global__ __launch_bounds__(256) void attn_agg(
        float* __restrict__ x, const __half* __restrict__ xwh,
        const int* __restrict__ adj, const int* __restrict__ deg,
        const float* __restrict__ ah1r, const float* __restrict__ ah2r,
        float* __restrict__ ah1w, float* __restrict__ ah2w,
        const float* __restrict__ gw1, const float* __restrict__ gb1,
        const float* __restrict__ gw2, const float* __restrict__ gb2) {
    int w    = threadIdx.x >> 6;       // wave 0..3
    int lane = threadIdx.x & 63;
    int s = blockIdx.x & 7;
    int i = (blockIdx.x >> 3) * 4 + w;
    int r = s * Nn + i;

    __shared__ float2 pn[4][MAXDEG];   // per-wave (p, j) slab

    int d = deg[r]; if (d > MAXDEG) d = MAXDEG;

    // ---- softmax over neighbor list (this wave, 64 lanes) ----
    float a1 = ah1r[r];
    const int* al = adj + (size_t)r * MAXDEG;
    const float* ah2s = ah2r + (size_t)s * Nn;
    int jlo = 0, jhi = 0;
    float elo = -INFINITY, ehi = -INFINITY;
    if (lane < d) {
        jlo = al[lane];
        float e = a1 + ah2s[jlo];
        elo = e > 0.f ? e : 0.2f * e;              // leaky_relu(0.2)
    }
    if (lane + 64 < d) {
        jhi = al[lane + 64];
        float e = a1 + ah2s[jhi];
        ehi = e > 0.f ? e : 0.2f * e;
    }
    float m = fmaxf(elo, ehi);
    #pragma unroll
    for (int o = 32; o > 0; o >>= 1) m = fmaxf(m, __shfl_xor(m, o));
    float exlo = (lane < d)      ? __expf(elo - m) : 0.f;
    float exhi = (lane + 64 < d) ? __expf(ehi - m) : 0.f;
    float sum = exlo + exhi;
    #pragma unroll
    for (int o = 32; o > 0; o >>= 1) sum += __shfl_xor(sum, o);
    float inv = (d > 0) ? 1.0f / sum : 0.f;

    // publish (p, j) — all 128 entries written (zero-padded past d)
    pn[w][lane]      = make_float2(exlo, __int_as_float(jlo));
    pn[w][lane + 64] = make_float2(exhi, __int_as_float(jhi));
    // no __syncthreads: same-wave LDS write->read, compiler emits lgkmcnt

    // ---- software-pipelined sparse aggregate ----
    const uint4* xwu = (const uint4*)(xwh + (size_t)s * Nn * Dn);  // 16/row
    int g = lane >> 4;
    int f = lane & 15;
    float accA[4] = {0.f, 0.f, 0.f, 0.f};
    float accB[4] = {0.f, 0.f, 0.f, 0.f};
    int dpad = (d + 15) & ~15;

    float2 q0[4];
    uint4  v0[4];
    #pragma unroll
    for (int t = 0; t < 4; ++t) q0[t] = pn[w][4 * t + g];
    #pragma unroll
    for (int t = 0; t < 4; ++t)
        v0[t] = xwu[(size_t)__float_as_int(q0[t].y) * 16 + f];

    for (int base = 16; base < dpad; base += 16) {
        float2 q1[4];
        uint4  v1[4];
        #pragma unroll
        for (int t = 0; t < 4; ++t) q1[t] = pn[w][base + 4 * t + g];
        #pragma unroll
        for (int t = 0; t < 4; ++t)
            v1[t] = xwu[(size_t)__float_as_int(q1[t].y) * 16 + f];
        #pragma unroll
        for (int t = 0; t < 4; ++t) {
            const __half* h = (const __half*)&v0[t];
            float p = q0[t].x;
            accA[0] = fmaf(p, __half2float(h[0]), accA[0]);
            accA[1] = fmaf(p, __half2float(h[1]), accA[1]);
            accA[2] = fmaf(p, __half2float(h[2]), accA[2]);
            accA[3] = fmaf(p, __half2float(h[3]), accA[3]);
            accB[0] = fmaf(p, __half2float(h[4]), accB[0]);
            accB[1] = fmaf(p, __half2float(h[5]), accB[1]);
            accB[2] = fmaf(p, __half2float(h[6]), accB[2]);
            accB[3] = fmaf(p, __half2float(h[7]), accB[3]);
        }
        #pragma unroll
        for (int t = 0; t < 4; ++t) { q0[t] = q1[t]; v0[t] = v1[t]; }
    }
    #pragma unroll
    for (int t = 0; t < 4; ++t) {
        const __half* h = (const __half*)&v0[t];
        float p = q0[t].x;
        accA[0] = fmaf(p, __half2float(h[0]), accA[0]);
        accA[1] = fmaf(p, __half2float(h[1]), accA[1]);
        accA[2] = fmaf(p, __half2float(h[2]), accA[2]);
        accA[3] = fmaf(p, __half2float(h[3]), accA[3]);
        accB[0] = fmaf(p, __half2float(h[4]), accB[0]);
        accB[1] = fmaf(p, __half2float(h[5]), accB[1]);
        accB[2] = fmaf(p, __half2float(h[6]), accB[2]);
        accB[3] = fmaf(p, __half2float(h[7]), accB[3]);
    }
    // fold the 4 groups (after this every lane holds the full sum)
    #pragma unroll
    for (int e = 0; e < 4; ++e) {
        accA[e] += __shfl_xor(accA[e], 16);
        accA[e] += __shfl_xor(accA[e], 32);
        accB[e] += __shfl_xor(accB[e], 16);
        accB[e] += __shfl_xor(accB[e], 32);
    }

    // ---- residual + ELU + store + next-iter ah (lanes 0..15) ----
    if (lane < 16) {
        float4* x4 = (float4*)(x + (size_t)r * Dn);
        float4 vA = x4[2 * lane], vB = x4[2 * lane + 1];
        float4 tA, tB, rA, rB;
        tA.x = vA.x + accA[0] * inv;  tA.y = vA.y + accA[1] * inv;
        tA.z = vA.z + accA[2] * inv;  tA.w = vA.w + accA[3] * inv;
        tB.x = vB.x + accB[0] * inv;  tB.y = vB.y + accB[1] * inv;
        tB.z = vB.z + accB[2] * inv;  tB.w = vB.w + accB[3] * inv;
        rA.x = tA.x > 0.f ? tA.x : (expf(tA.x) - 1.f);
        rA.y = tA.y > 0.f ? tA.y : (expf(tA.y) - 1.f);
        rA.z = tA.z > 0.f ? tA.z : (expf(tA.z) - 1.f);
        rA.w = tA.w > 0.f ? tA.w : (expf(tA.w) - 1.f);
        rB.x = tB.x > 0.f ? tB.x : (expf(tB.x) - 1.f);
        rB.y = tB.y > 0.f ? tB.y : (expf(tB.y) - 1.f);
        rB.z = tB.z > 0.f ? tB.z : (expf(tB.z) - 1.f);
        rB.w = tB.w > 0.f ? tB.w : (expf(tB.w) - 1.f);
        x4[2 * lane]     = rA;
        x4[2 * lane + 1] = rB;

        // ah for next iteration (row is in rA/rB across lanes 0..15)
        const float4* w14 = (const float4*)gw1;
        const float4* w24 = (const float4*)gw2;
        float4 wa = w14[2 * lane], wb = w14[2 * lane + 1];
        float4 ua = w24[2 * lane], ub = w24[2 * lane + 1];
        float p1 = rA.x * wa.x + rA.y * wa.y + rA.z * wa.z + rA.w * wa.w
                 + rB.x * wb.x + rB.y * wb.y + rB.z * wb.z + rB.w * wb.w;
        float p2 = rA.x * ua.x + rA.y * ua.y + rA.z * ua.z + rA.w * ua.w
                 + rB.x * ub.x + rB.y * ub.y + rB.z * ub.z + rB.w * ub.w;
        #pragma unroll
        for (int o = 8; o >= 1; o >>= 1) {
            p1 += __shfl_xor(p1, o);
            p2 += __shfl_xor(p2, o);
        }
        if (lane == 0) {
            ah1w[r] = p1 + gb1[0];
            ah2w[r] = p2 + gb2[0];
        }
    }
}

// ---------------------------------------------------------------------------
// Stage-1 reduction over rows: 32 chunks of 64 rows per batch, fwd+rev fused.
__global__ void reduce_partial(const float* __restrict__ x, float* __restrict__ part) {
    int b = blockIdx.x >> 5;
    int c = blockIdx.x & 31;
    int tid = threadIdx.x;                     // 0..127 = d
    const float* xf = x + ((size_t)(b * Nn) + c * 64) * Dn;
    const float* xr = x + ((size_t)((4 + b) * Nn) + c * 64) * Dn;
    float sv = 0.f;
    for (int i = 0; i < 64; ++i)
        sv += xf[(size_t)i * Dn + tid] + xr[(size_t)i * Dn + tid];
    part[(size_t)blockIdx.x * Dn + tid] = sv;
}

// ---------------------------------------------------------------------------
// Stage-2: mid[b] = sum of partials; out[b] = mid @ Wout + bout
__global__ void final_out(const float* __restrict__ part,
                          const float* __restrict__ Wout, const float* __restrict__ bout,
                          float* __restrict__ out) {
    int b = blockIdx.x;
    int tid = threadIdx.x;                     // 128 threads
    __shared__ float mid[Dn];
    float sv = 0.f;
    for (int c = 0; c < 32; ++c) sv += part[(size_t)(b * 32 + c) * Dn + tid];
    mid[tid] = sv;
    __syncthreads();
    if (tid < OUTn) {
        float o = bout[tid];
        #pragma unroll 4
        for (int k = 0; k < Dn; ++k) o = fmaf(mid[k], Wout[k * OUTn + tid], o);
        out[b * OUTn + tid] = o;
    }
}

// ---------------------------------------------------------------------------
extern "C" void kernel_launch(void* const* d_in, const int* in_sizes, int n_in,
                              void* d_out, int out_size, void* d_ws, size_t ws_size,
                              hipStream_t stream) {
    const float* INPUT = (const float*)d_in[0];
    const float* CFG   = (const float*)d_in[1];
    // d_in[2] = LFG, unused by the forward pass
    const float* w1    = (const float*)d_in[3];
    const float* b1    = (const float*)d_in[4];
    const float* w2    = (const float*)d_in[5];
    const float* b2    = (const float*)d_in[6];
    const float* Wm    = (const float*)d_in[7];
    const float* Wout  = (const float*)d_in[8];
    const float* bout  = (const float*)d_in[9];
    float* out = (float*)d_out;

    // workspace layout (~22.6 MB)
    float*  x    = (float*)d_ws;                          // Sn*Nn*Dn   (8 MB)
    __half* xwh  = (__half*)(x + (size_t)Sn * Nn * Dn);   // Sn*Nn*Dn   (4 MB)
    int*    adj  = (int*)(xwh + (size_t)Sn * Nn * Dn);    // Sn*Nn*MAXDEG (8 MB)
    int*    deg  = adj + (size_t)Sn * Nn * MAXDEG;        // Sn*Nn
    float*  ah1a = (float*)(deg + Sn * Nn);               // Sn*Nn
    float*  ah2a = ah1a + Sn * Nn;                        // Sn*Nn
    float*  ah1b = ah2a + Sn * Nn;                        // Sn*Nn
    float*  ah2b = ah1b + Sn * Nn;                        // Sn*Nn
    float*  part = ah2b + Sn * Nn;                        // Bn*32*Dn
    unsigned long long* bits = (unsigned long long*)(part + Bn * 32 * Dn); // 2 MB

    fwd_bits_init<<<(Bn * Nn) / 4 + (Bn * Nn) / 8, 256, 0, stream>>>(
        (const float4*)CFG, bits, adj, deg, (const float4*)INPUT, (float4*)x,
        w1, b1, w2, b2, ah1a, ah2a);
    rev_adj<<<(Bn * Nn) / 4, 256, 0, stream>>>(bits, adj, deg);

    for (int it = 0; it < NITER; ++it) {
        gemm_xw<<<(Sn * Nn) / 8, 128, 0, stream>>>(x, Wm, xwh);
        const float* r1 = (it & 1) ? ah1b : ah1a;
        const float* r2 = (it & 1) ? ah2b : ah2a;
        float* w1p = (it & 1) ? ah1a : ah1b;
        float* w2p = (it & 1) ? ah2a : ah2b;
        attn_agg<<<(Sn * Nn) / 4, 256, 0, stream>>>(
            x, xwh, adj, deg, r1, r2, w1p, w2p, w1, b1, w2, b2);
    }

    reduce_partial<<<Bn * 32, 128, 0, stream>>>(x, part);
    final_out     <<<Bn, 128, 0, stream>>>(part, Wout, bout, out);
}

// Round 10
// 189.004 us; speedup vs baseline: 1.5259x; 1.5259x over previous
//
#include <hip/hip_runtime.h>
#include <hip/hip_fp16.h>
#include <cstdint>
#include <cstddef>

// Problem constants (match reference)
#define Bn 4
#define Nn 2048
#define Dn 128
#define OUTn 64
#define Sn 8          // 4 batches x {fwd, rev}
#define MAXDEG 128    // binomial(2048, 1/32): mean 64, sd 7.9; max over 16K rows ~99
#define NITER 3

// ---------------------------------------------------------------------------
// deposit low 16 bits of x at bit positions 0,4,8,...,60
__device__ __forceinline__ unsigned long long spread4(unsigned long long x) {
    x &= 0xFFFFull;
    x = (x | (x << 24)) & 0x000000FF000000FFull;
    x = (x | (x << 12)) & 0x000F000F000F000Full;
    x = (x | (x << 6))  & 0x0303030303030303ull;
    x = (x | (x << 3))  & 0x1111111111111111ull;
    return x;
}

// ---------------------------------------------------------------------------
// Blocks [0, 4096): one wave per forward row (b,i): forward adjacency
// (sorted, deterministic), degree, and the column-major bitmask.
// Blocks [4096, 5120): row-organized init: x[s]=relu(INPUT[b]) for s=b,b+4
// AND the iteration-0 attention scalars ah1/ah2 (32-lane shfl reduce).
__global__ void fwd_bits_init(const float4* __restrict__ cfg4,
                              unsigned long long* __restrict__ bits,
                              int* __restrict__ adj, int* __restrict__ deg,
                              const float4* __restrict__ in4, float4* __restrict__ x4,
                              const float* __restrict__ w1, const float* __restrict__ b1,
                              const float* __restrict__ w2, const float* __restrict__ b2,
                              float* __restrict__ ah1, float* __restrict__ ah2) {
    if (blockIdx.x >= (Bn * Nn) / 4) {
        int blk = blockIdx.x - (Bn * Nn) / 4;         // 0..1023
        int t = threadIdx.x;
        int row = blk * 8 + (t >> 5);                 // [0, Bn*Nn)
        int q   = t & 31;                             // feature quad
        float4 v = in4[(size_t)row * 32 + q];
        v.x = v.x > 0.f ? v.x : 0.f;
        v.y = v.y > 0.f ? v.y : 0.f;
        v.z = v.z > 0.f ? v.z : 0.f;
        v.w = v.w > 0.f ? v.w : 0.f;
        x4[(size_t)row * 32 + q] = v;
        x4[(size_t)(Bn * Nn * Dn) / 4 + (size_t)row * 32 + q] = v;
        const float4* w14 = (const float4*)w1;
        const float4* w24 = (const float4*)w2;
        float4 wa = w14[q], wb = w24[q];
        float p1 = v.x * wa.x + v.y * wa.y + v.z * wa.z + v.w * wa.w;
        float p2 = v.x * wb.x + v.y * wb.y + v.z * wb.z + v.w * wb.w;
        #pragma unroll
        for (int o = 16; o >= 1; o >>= 1) {
            p1 += __shfl_xor(p1, o);
            p2 += __shfl_xor(p2, o);
        }
        if (q == 0) {
            float a1 = p1 + b1[0], a2 = p2 + b2[0];
            ah1[row] = a1; ah1[Bn * Nn + row] = a1;   // fwd slot b, rev slot 4+b
            ah2[row] = a2; ah2[Bn * Nn + row] = a2;
        }
        return;
    }
    int row  = blockIdx.x * 4 + (threadIdx.x >> 6);   // [0, Bn*Nn)
    int lane = threadIdx.x & 63;
    int b = row >> 11;
    int i = row & (Nn - 1);
    const float4* crow = cfg4 + (size_t)row * (Nn / 4);
    int* dst = adj + (size_t)row * MAXDEG;
    int cnt = 0;
    for (int j0 = 0; j0 < Nn; j0 += 256) {
        float4 v = crow[(j0 >> 2) + lane];
        int nib = (v.x != 0.f) | ((v.y != 0.f) << 1) |
                  ((v.z != 0.f) << 2) | ((v.w != 0.f) << 3);
        unsigned long long m0 = __ballot(nib & 1);
        unsigned long long m1 = __ballot(nib & 2);
        unsigned long long m2 = __ballot(nib & 4);
        unsigned long long m3 = __ballot(nib & 8);
        unsigned long long below = (1ull << lane) - 1ull;
        int off = __popcll(m0 & below) + __popcll(m1 & below) +
                  __popcll(m2 & below) + __popcll(m3 & below);
        int total = __popcll(m0) + __popcll(m1) + __popcll(m2) + __popcll(m3);
        int base = cnt + off;
        int col = j0 + 4 * lane;
        if (nib & 1) { if (base < MAXDEG) dst[base] = col;     base++; }
        if (nib & 2) { if (base < MAXDEG) dst[base] = col + 1; base++; }
        if (nib & 4) { if (base < MAXDEG) dst[base] = col + 2; base++; }
        if (nib & 8) { if (base < MAXDEG) dst[base] = col + 3; base++; }
        if (lane < 4) {
            int sh = lane << 4;
            unsigned long long w = spread4(m0 >> sh) | (spread4(m1 >> sh) << 1) |
                                   (spread4(m2 >> sh) << 2) | (spread4(m3 >> sh) << 3);
            int jw = (j0 >> 6) + lane;
            bits[((size_t)(b * 32 + jw)) * Nn + i] = w;
        }
        cnt += total;
    }
    if (lane == 0) deg[row] = (cnt < MAXDEG ? cnt : MAXDEG);
}

// ---------------------------------------------------------------------------
// One wave per reverse row (b,j): read plane bits[b][j>>6][*] contiguously;
// ballot-compact ascending i. Deterministic and sorted.
__global__ void rev_adj(const unsigned long long* __restrict__ bits,
                        int* __restrict__ adj, int* __restrict__ deg) {
    int r    = blockIdx.x * 4 + (threadIdx.x >> 6);   // [0, Bn*Nn)
    int lane = threadIdx.x & 63;
    int b = r >> 11;
    int j = r & (Nn - 1);
    const unsigned long long* col = bits + ((size_t)(b * 32 + (j >> 6))) * Nn;
    int bit = j & 63;
    int out_r = (Bn + b) * Nn + j;
    int* dst = adj + (size_t)out_r * MAXDEG;
    int cnt = 0;
    for (int i0 = 0; i0 < Nn; i0 += 64) {
        unsigned long long word = col[i0 + lane];
        bool e = (word >> bit) & 1;
        unsigned long long m = __ballot(e);
        if (e) {
            int pos = cnt + __popcll(m & ((1ull << lane) - 1ull));
            if (pos < MAXDEG) dst[pos] = i0 + lane;
        }
        cnt += __popcll(m);
    }
    if (lane == 0) deg[out_r] = (cnt < MAXDEG ? cnt : MAXDEG);
}

// ---------------------------------------------------------------------------
// Pure streaming GEMM: xw = fp16(x @ W). 8 rows per 128-thread block; x-row
// loads wave-uniform (scalar path), W loads coalesced + cache resident.
__global__ void gemm_xw(const float* __restrict__ x, const float* __restrict__ W,
                        __half* __restrict__ xwh) {
    int c = threadIdx.x;                              // column 0..127
    size_t rbase = (size_t)blockIdx.x * 8 * Dn;
    const float* x0 = x + rbase;
    float a0 = 0.f, a1 = 0.f, a2 = 0.f, a3 = 0.f;
    float a4 = 0.f, a5 = 0.f, a6 = 0.f, a7 = 0.f;
    #pragma unroll 4
    for (int k = 0; k < Dn; ++k) {
        float w = W[k * Dn + c];
        a0 = fmaf(x0[0 * Dn + k], w, a0);
        a1 = fmaf(x0[1 * Dn + k], w, a1);
        a2 = fmaf(x0[2 * Dn + k], w, a2);
        a3 = fmaf(x0[3 * Dn + k], w, a3);
        a4 = fmaf(x0[4 * Dn + k], w, a4);
        a5 = fmaf(x0[5 * Dn + k], w, a5);
        a6 = fmaf(x0[6 * Dn + k], w, a6);
        a7 = fmaf(x0[7 * Dn + k], w, a7);
    }
    xwh[rbase + 0 * Dn + c] = __float2half(a0);
    xwh[rbase + 1 * Dn + c] = __float2half(a1);
    xwh[rbase + 2 * Dn + c] = __float2half(a2);
    xwh[rbase + 3 * Dn + c] = __float2half(a3);
    xwh[rbase + 4 * Dn + c] = __float2half(a4);
    xwh[rbase + 5 * Dn + c] = __float2half(a5);
    xwh[rbase + 6 * Dn + c] = __float2half(a6);
    xwh[rbase + 7 * Dn + c] = __float2half(a7);
}

// ---------------------------------------------------------------------------
// Fused: masked softmax + sparse aggregate of fp16 xw + residual + ELU +
// next-iteration ah1/ah2 (double-buffered). ONE WAVE PER ROW, no barriers.
// Gather: TRUE ping-pong (disjoint register sets A/B, no rotation copies):
// {stage B; FMA A; stage A-next; FMA B} -> 8 loads continuously in flight,
// each FMA waits only vmcnt(4). pn is padded to MAXDEG+32 zero entries so
// the A-next prefetch is unconditional (p=0 rows are harmless).
__global__ __launch_bounds__(256) void attn_agg(
        float* __restrict__ x, const __half* __restrict__ xwh,
        const int* __restrict__ adj, const int* __restrict__ deg,
        const float* __restrict__ ah1r, const float* __restrict__ ah2r,
        float* __restrict__ ah1w, float* __restrict__ ah2w,
        const float* __restrict__ gw1, const float* __restrict__ gb1,
        const float* __restrict__ gw2, const float* __restrict__ gb2) {
    int w    = threadIdx.x >> 6;       // wave 0..3
    int lane = threadIdx.x & 63;
    int s = blockIdx.x & 7;
    int i = (blockIdx.x >> 3) * 4 + w;
    int r = s * Nn + i;

    __shared__ float2 pn[4][MAXDEG + 32];   // per-wave (p, j) slab, zero-padded

    int d = deg[r]; if (d > MAXDEG) d = MAXDEG;

    // ---- softmax over neighbor list (this wave, 64 lanes) ----
    float a1 = ah1r[r];
    const int* al = adj + (size_t)r * MAXDEG;
    const float* ah2s = ah2r + (size_t)s * Nn;
    int jlo = 0, jhi = 0;
    float elo = -INFINITY, ehi = -INFINITY;
    if (lane < d) {
        jlo = al[lane];
        float e = a1 + ah2s[jlo];
        elo = e > 0.f ? e : 0.2f * e;              // leaky_relu(0.2)
    }
    if (lane + 64 < d) {
        jhi = al[lane + 64];
        float e = a1 + ah2s[jhi];
        ehi = e > 0.f ? e : 0.2f * e;
    }
    float m = fmaxf(elo, ehi);
    #pragma unroll
    for (int o = 32; o > 0; o >>= 1) m = fmaxf(m, __shfl_xor(m, o));
    float exlo = (lane < d)      ? __expf(elo - m) : 0.f;
    float exhi = (lane + 64 < d) ? __expf(ehi - m) : 0.f;
    float sum = exlo + exhi;
    #pragma unroll
    for (int o = 32; o > 0; o >>= 1) sum += __shfl_xor(sum, o);
    float inv = (d > 0) ? 1.0f / sum : 0.f;

    // publish (p, j) — 128 entries + 32 zero pad (no barrier: same-wave DS)
    pn[w][lane]      = make_float2(exlo, __int_as_float(jlo));
    pn[w][lane + 64] = make_float2(exhi, __int_as_float(jhi));
    if (lane < 32) pn[w][MAXDEG + lane] = make_float2(0.f, 0.f);

    // ---- ping-pong sparse aggregate ----
    const uint4* xwu = (const uint4*)(xwh + (size_t)s * Nn * Dn);  // 16/row
    int g = lane >> 4;
    int f = lane & 15;
    float accA[4] = {0.f, 0.f, 0.f, 0.f};
    float accB[4] = {0.f, 0.f, 0.f, 0.f};
    int dpad = (d + 31) & ~31;

    float2 qA[4], qB[4];
    uint4  vA[4], vB[4];
    #pragma unroll
    for (int t = 0; t < 4; ++t) qA[t] = pn[w][4 * t + g];
    #pragma unroll
    for (int t = 0; t < 4; ++t)
        vA[t] = xwu[(size_t)__float_as_int(qA[t].y) * 16 + f];

    for (int base = 0; base < dpad; base += 32) {
        // stage B (neighbors base+16 .. base+31)
        #pragma unroll
        for (int t = 0; t < 4; ++t) qB[t] = pn[w][base + 16 + 4 * t + g];
        #pragma unroll
        for (int t = 0; t < 4; ++t)
            vB[t] = xwu[(size_t)__float_as_int(qB[t].y) * 16 + f];
        // consume A (waits only on its own 4 loads)
        #pragma unroll
        for (int t = 0; t < 4; ++t) {
            const __half* h = (const __half*)&vA[t];
            float p = qA[t].x;
            accA[0] = fmaf(p, __half2float(h[0]), accA[0]);
            accA[1] = fmaf(p, __half2float(h[1]), accA[1]);
            accA[2] = fmaf(p, __half2float(h[2]), accA[2]);
            accA[3] = fmaf(p, __half2float(h[3]), accA[3]);
            accB[0] = fmaf(p, __half2float(h[4]), accB[0]);
            accB[1] = fmaf(p, __half2float(h[5]), accB[1]);
            accB[2] = fmaf(p, __half2float(h[6]), accB[2]);
            accB[3] = fmaf(p, __half2float(h[7]), accB[3]);
        }
        // stage A for next iteration (unconditional; pad region is zeros)
        #pragma unroll
        for (int t = 0; t < 4; ++t) qA[t] = pn[w][base + 32 + 4 * t + g];
        #pragma unroll
        for (int t = 0; t < 4; ++t)
            vA[t] = xwu[(size_t)__float_as_int(qA[t].y) * 16 + f];
        // consume B
        #pragma unroll
        for (int t = 0; t < 4; ++t) {
            const __half* h = (const __half*)&vB[t];
            float p = qB[t].x;
            accA[0] = fmaf(p, __half2float(h[0]), accA[0]);
            accA[1] = fmaf(p, __half2float(h[1]), accA[1]);
            accA[2] = fmaf(p, __half2float(h[2]), accA[2]);
            accA[3] = fmaf(p, __half2float(h[3]), accA[3]);
            accB[0] = fmaf(p, __half2float(h[4]), accB[0]);
            accB[1] = fmaf(p, __half2float(h[5]), accB[1]);
            accB[2] = fmaf(p, __half2float(h[6]), accB[2]);
            accB[3] = fmaf(p, __half2float(h[7]), accB[3]);
        }
    }
    // fold the 4 groups (after this every lane holds the full sum)
    #pragma unroll
    for (int e = 0; e < 4; ++e) {
        accA[e] += __shfl_xor(accA[e], 16);
        accA[e] += __shfl_xor(accA[e], 32);
        accB[e] += __shfl_xor(accB[e], 16);
        accB[e] += __shfl_xor(accB[e], 32);
    }

    // ---- residual + ELU + store + next-iter ah (lanes 0..15) ----
    if (lane < 16) {
        float4* x4 = (float4*)(x + (size_t)r * Dn);
        float4 vA4 = x4[2 * lane], vB4 = x4[2 * lane + 1];
        float4 tA, tB, rA, rB;
        tA.x = vA4.x + accA[0] * inv;  tA.y = vA4.y + accA[1] * inv;
        tA.z = vA4.z + accA[2] * inv;  tA.w = vA4.w + accA[3] * inv;
        tB.x = vB4.x + accB[0] * inv;  tB.y = vB4.y + accB[1] * inv;
        tB.z = vB4.z + accB[2] * inv;  tB.w = vB4.w + accB[3] * inv;
        rA.x = tA.x > 0.f ? tA.x : (expf(tA.x) - 1.f);
        rA.y = tA.y > 0.f ? tA.y : (expf(tA.y) - 1.f);
        rA.z = tA.z > 0.f ? tA.z : (expf(tA.z) - 1.f);
        rA.w = tA.w > 0.f ? tA.w : (expf(tA.w) - 1.f);
        rB.x = tB.x > 0.f ? tB.x : (expf(tB.x) - 1.f);
        rB.y = tB.y > 0.f ? tB.y : (expf(tB.y) - 1.f);
        rB.z = tB.z > 0.f ? tB.z : (expf(tB.z) - 1.f);
        rB.w = tB.w > 0.f ? tB.w : (expf(tB.w) - 1.f);
        x4[2 * lane]     = rA;
        x4[2 * lane + 1] = rB;

        // ah for next iteration (row is in rA/rB across lanes 0..15)
        const float4* w14 = (const float4*)gw1;
        const float4* w24 = (const float4*)gw2;
        float4 wa = w14[2 * lane], wb = w14[2 * lane + 1];
        float4 ua = w24[2 * lane], ub = w24[2 * lane + 1];
        float p1 = rA.x * wa.x + rA.y * wa.y + rA.z * wa.z + rA.w * wa.w
                 + rB.x * wb.x + rB.y * wb.y + rB.z * wb.z + rB.w * wb.w;
        float p2 = rA.x * ua.x + rA.y * ua.y + rA.z * ua.z + rA.w * ua.w
                 + rB.x * ub.x + rB.y * ub.y + rB.z * ub.z + rB.w * ub.w;
        #pragma unroll
        for (int o = 8; o >= 1; o >>= 1) {
            p1 += __shfl_xor(p1, o);
            p2 += __shfl_xor(p2, o);
        }
        if (lane == 0) {
            ah1w[r] = p1 + gb1[0];
            ah2w[r] = p2 + gb2[0];
        }
    }
}

// ---------------------------------------------------------------------------
// Stage-1 reduction over rows: 32 chunks of 64 rows per batch, fwd+rev fused.
__global__ void reduce_partial(const float* __restrict__ x, float* __restrict__ part) {
    int b = blockIdx.x >> 5;
    int c = blockIdx.x & 31;
    int tid = threadIdx.x;                     // 0..127 = d
    const float* xf = x + ((size_t)(b * Nn) + c * 64) * Dn;
    const float* xr = x + ((size_t)((4 + b) * Nn) + c * 64) * Dn;
    float sv = 0.f;
    for (int i = 0; i < 64; ++i)
        sv += xf[(size_t)i * Dn + tid] + xr[(size_t)i * Dn + tid];
    part[(size_t)blockIdx.x * Dn + tid] = sv;
}

// ---------------------------------------------------------------------------
// Stage-2: mid[b] = sum of partials; out[b] = mid @ Wout + bout
__global__ void final_out(const float* __restrict__ part,
                          const float* __restrict__ Wout, const float* __restrict__ bout,
                          float* __restrict__ out) {
    int b = blockIdx.x;
    int tid = threadIdx.x;                     // 128 threads
    __shared__ float mid[Dn];
    float sv = 0.f;
    for (int c = 0; c < 32; ++c) sv += part[(size_t)(b * 32 + c) * Dn + tid];
    mid[tid] = sv;
    __syncthreads();
    if (tid < OUTn) {
        float o = bout[tid];
        #pragma unroll 4
        for (int k = 0; k < Dn; ++k) o = fmaf(mid[k], Wout[k * OUTn + tid], o);
        out[b * OUTn + tid] = o;
    }
}

// ---------------------------------------------------------------------------
extern "C" void kernel_launch(void* const* d_in, const int* in_sizes, int n_in,
                              void* d_out, int out_size, void* d_ws, size_t ws_size,
                              hipStream_t stream) {
    const float* INPUT = (const float*)d_in[0];
    const float* CFG   = (const float*)d_in[1];
    // d_in[2] = LFG, unused by the forward pass
    const float* w1    = (const float*)d_in[3];
    const float* b1    = (const float*)d_in[4];
    const float* w2    = (const float*)d_in[5];
    const float* b2    = (const float*)d_in[6];
    const float* Wm    = (const float*)d_in[7];
    const float* Wout  = (const float*)d_in[8];
    const float* bout  = (const float*)d_in[9];
    float* out = (float*)d_out;

    // workspace layout (~22.6 MB)
    float*  x    = (float*)d_ws;                          // Sn*Nn*Dn   (8 MB)
    __half* xwh  = (__half*)(x + (size_t)Sn * Nn * Dn);   // Sn*Nn*Dn   (4 MB)
    int*    adj  = (int*)(xwh + (size_t)Sn * Nn * Dn);    // Sn*Nn*MAXDEG (8 MB)
    int*    deg  = adj + (size_t)Sn * Nn * MAXDEG;        // Sn*Nn
    float*  ah1a = (float*)(deg + Sn * Nn);               // Sn*Nn
    float*  ah2a = ah1a + Sn * Nn;                        // Sn*Nn
    float*  ah1b = ah2a + Sn * Nn;                        // Sn*Nn
    float*  ah2b = ah1b + Sn * Nn;                        // Sn*Nn
    float*  part = ah2b + Sn * Nn;                        // Bn*32*Dn
    unsigned long long* bits = (unsigned long long*)(part + Bn * 32 * Dn); // 2 MB

    fwd_bits_init<<<(Bn * Nn) / 4 + (Bn * Nn) / 8, 256, 0, stream>>>(
        (const float4*)CFG, bits, adj, deg, (const float4*)INPUT, (float4*)x,
        w1, b1, w2, b2, ah1a, ah2a);
    rev_adj<<<(Bn * Nn) / 4, 256, 0, stream>>>(bits, adj, deg);

    for (int it = 0; it < NITER; ++it) {
        gemm_xw<<<(Sn * Nn) / 8, 128, 0, stream>>>(x, Wm, xwh);
        const float* r1 = (it & 1) ? ah1b : ah1a;
        const float* r2 = (it & 1) ? ah2b : ah2a;
        float* w1p = (it & 1) ? ah1a : ah1b;
        float* w2p = (it & 1) ? ah2a : ah2b;
        attn_agg<<<(Sn * Nn) / 4, 256, 0, stream>>>(
            x, xwh, adj, deg, r1, r2, w1p, w2p, w1, b1, w2, b2);
    }

    reduce_partial<<<Bn * 32, 128, 0, stream>>>(x, part);
    final_out     <<<Bn, 128, 0, stream>>>(part, Wout, bout, out);
}

// Round 11
// 187.929 us; speedup vs baseline: 1.5346x; 1.0057x over previous
//
#include <hip/hip_runtime.h>
#include <hip/hip_fp16.h>
#include <cstdint>
#include <cstddef>

// Problem constants (match reference)
#define Bn 4
#define Nn 2048
#define Dn 128
#define OUTn 64
#define Sn 8          // 4 batches x {fwd, rev}
#define MAXDEG 128    // binomial(2048, 1/32): mean 64, sd 7.9; max over 16K rows ~99
#define NITER 3

// ---------------------------------------------------------------------------
// deposit low 16 bits of x at bit positions 0,4,8,...,60
__device__ __forceinline__ unsigned long long spread4(unsigned long long x) {
    x &= 0xFFFFull;
    x = (x | (x << 24)) & 0x000000FF000000FFull;
    x = (x | (x << 12)) & 0x000F000F000F000Full;
    x = (x | (x << 6))  & 0x0303030303030303ull;
    x = (x | (x << 3))  & 0x1111111111111111ull;
    return x;
}

// ---------------------------------------------------------------------------
// Blocks [0, 4096): one wave per forward row (b,i): forward adjacency
// (sorted, deterministic), degree, and the column-major bitmask.
// Blocks [4096, 5120): row-organized init: x[s]=relu(INPUT[b]) for s=b,b+4
// AND the iteration-0 attention scalars ah1/ah2 (32-lane shfl reduce).
__global__ void fwd_bits_init(const float4* __restrict__ cfg4,
                              unsigned long long* __restrict__ bits,
                              int* __restrict__ adj, int* __restrict__ deg,
                              const float4* __restrict__ in4, float4* __restrict__ x4,
                              const float* __restrict__ w1, const float* __restrict__ b1,
                              const float* __restrict__ w2, const float* __restrict__ b2,
                              float* __restrict__ ah1, float* __restrict__ ah2) {
    if (blockIdx.x >= (Bn * Nn) / 4) {
        int blk = blockIdx.x - (Bn * Nn) / 4;         // 0..1023
        int t = threadIdx.x;
        int row = blk * 8 + (t >> 5);                 // [0, Bn*Nn)
        int q   = t & 31;                             // feature quad
        float4 v = in4[(size_t)row * 32 + q];
        v.x = v.x > 0.f ? v.x : 0.f;
        v.y = v.y > 0.f ? v.y : 0.f;
        v.z = v.z > 0.f ? v.z : 0.f;
        v.w = v.w > 0.f ? v.w : 0.f;
        x4[(size_t)row * 32 + q] = v;
        x4[(size_t)(Bn * Nn * Dn) / 4 + (size_t)row * 32 + q] = v;
        const float4* w14 = (const float4*)w1;
        const float4* w24 = (const float4*)w2;
        float4 wa = w14[q], wb = w24[q];
        float p1 = v.x * wa.x + v.y * wa.y + v.z * wa.z + v.w * wa.w;
        float p2 = v.x * wb.x + v.y * wb.y + v.z * wb.z + v.w * wb.w;
        #pragma unroll
        for (int o = 16; o >= 1; o >>= 1) {
            p1 += __shfl_xor(p1, o);
            p2 += __shfl_xor(p2, o);
        }
        if (q == 0) {
            float a1 = p1 + b1[0], a2 = p2 + b2[0];
            ah1[row] = a1; ah1[Bn * Nn + row] = a1;   // fwd slot b, rev slot 4+b
            ah2[row] = a2; ah2[Bn * Nn + row] = a2;
        }
        return;
    }
    int row  = blockIdx.x * 4 + (threadIdx.x >> 6);   // [0, Bn*Nn)
    int lane = threadIdx.x & 63;
    int b = row >> 11;
    int i = row & (Nn - 1);
    const float4* crow = cfg4 + (size_t)row * (Nn / 4);
    int* dst = adj + (size_t)row * MAXDEG;
    int cnt = 0;
    for (int j0 = 0; j0 < Nn; j0 += 256) {
        float4 v = crow[(j0 >> 2) + lane];
        int nib = (v.x != 0.f) | ((v.y != 0.f) << 1) |
                  ((v.z != 0.f) << 2) | ((v.w != 0.f) << 3);
        unsigned long long m0 = __ballot(nib & 1);
        unsigned long long m1 = __ballot(nib & 2);
        unsigned long long m2 = __ballot(nib & 4);
        unsigned long long m3 = __ballot(nib & 8);
        unsigned long long below = (1ull << lane) - 1ull;
        int off = __popcll(m0 & below) + __popcll(m1 & below) +
                  __popcll(m2 & below) + __popcll(m3 & below);
        int total = __popcll(m0) + __popcll(m1) + __popcll(m2) + __popcll(m3);
        int base = cnt + off;
        int col = j0 + 4 * lane;
        if (nib & 1) { if (base < MAXDEG) dst[base] = col;     base++; }
        if (nib & 2) { if (base < MAXDEG) dst[base] = col + 1; base++; }
        if (nib & 4) { if (base < MAXDEG) dst[base] = col + 2; base++; }
        if (nib & 8) { if (base < MAXDEG) dst[base] = col + 3; base++; }
        if (lane < 4) {
            int sh = lane << 4;
            unsigned long long w = spread4(m0 >> sh) | (spread4(m1 >> sh) << 1) |
                                   (spread4(m2 >> sh) << 2) | (spread4(m3 >> sh) << 3);
            int jw = (j0 >> 6) + lane;
            bits[((size_t)(b * 32 + jw)) * Nn + i] = w;
        }
        cnt += total;
    }
    if (lane == 0) deg[row] = (cnt < MAXDEG ? cnt : MAXDEG);
}

// ---------------------------------------------------------------------------
// Merged launch (both depend only on fwd_bits_init; disjoint outputs):
// Blocks [0, 2048):    xw = fp16(x @ W) for iteration 0 (8 rows/block).
// Blocks [2048, 6144): reverse adjacency: 2 waves/block, one reverse row
// each; read plane bits[b][j>>6][*] contiguously (L1-resident across 64
// consecutive rows); ballot-compact ascending i. Deterministic and sorted.
__global__ void gemm_rev(const float* __restrict__ x, const float* __restrict__ W,
                         __half* __restrict__ xwh,
                         const unsigned long long* __restrict__ bits,
                         int* __restrict__ adj, int* __restrict__ deg) {
    if (blockIdx.x < (Sn * Nn) / 8) {
        int c = threadIdx.x;                              // column 0..127
        size_t rbase = (size_t)blockIdx.x * 8 * Dn;
        const float* x0 = x + rbase;
        float a0 = 0.f, a1 = 0.f, a2 = 0.f, a3 = 0.f;
        float a4 = 0.f, a5 = 0.f, a6 = 0.f, a7 = 0.f;
        #pragma unroll 4
        for (int k = 0; k < Dn; ++k) {
            float w = W[k * Dn + c];
            a0 = fmaf(x0[0 * Dn + k], w, a0);
            a1 = fmaf(x0[1 * Dn + k], w, a1);
            a2 = fmaf(x0[2 * Dn + k], w, a2);
            a3 = fmaf(x0[3 * Dn + k], w, a3);
            a4 = fmaf(x0[4 * Dn + k], w, a4);
            a5 = fmaf(x0[5 * Dn + k], w, a5);
            a6 = fmaf(x0[6 * Dn + k], w, a6);
            a7 = fmaf(x0[7 * Dn + k], w, a7);
        }
        xwh[rbase + 0 * Dn + c] = __float2half(a0);
        xwh[rbase + 1 * Dn + c] = __float2half(a1);
        xwh[rbase + 2 * Dn + c] = __float2half(a2);
        xwh[rbase + 3 * Dn + c] = __float2half(a3);
        xwh[rbase + 4 * Dn + c] = __float2half(a4);
        xwh[rbase + 5 * Dn + c] = __float2half(a5);
        xwh[rbase + 6 * Dn + c] = __float2half(a6);
        xwh[rbase + 7 * Dn + c] = __float2half(a7);
        return;
    }
    int r    = (blockIdx.x - (Sn * Nn) / 8) * 2 + (threadIdx.x >> 6);  // [0, Bn*Nn)
    int lane = threadIdx.x & 63;
    int b = r >> 11;
    int j = r & (Nn - 1);
    const unsigned long long* col = bits + ((size_t)(b * 32 + (j >> 6))) * Nn;
    int bit = j & 63;
    int out_r = (Bn + b) * Nn + j;
    int* dst = adj + (size_t)out_r * MAXDEG;
    int cnt = 0;
    for (int i0 = 0; i0 < Nn; i0 += 64) {
        unsigned long long word = col[i0 + lane];
        bool e = (word >> bit) & 1;
        unsigned long long m = __ballot(e);
        if (e) {
            int pos = cnt + __popcll(m & ((1ull << lane) - 1ull));
            if (pos < MAXDEG) dst[pos] = i0 + lane;
        }
        cnt += __popcll(m);
    }
    if (lane == 0) deg[out_r] = (cnt < MAXDEG ? cnt : MAXDEG);
}

// ---------------------------------------------------------------------------
// Pure streaming GEMM: xw = fp16(x @ W). 8 rows per 128-thread block (used
// for iterations 1..NITER-1).
__global__ void gemm_xw(const float* __restrict__ x, const float* __restrict__ W,
                        __half* __restrict__ xwh) {
    int c = threadIdx.x;                              // column 0..127
    size_t rbase = (size_t)blockIdx.x * 8 * Dn;
    const float* x0 = x + rbase;
    float a0 = 0.f, a1 = 0.f, a2 = 0.f, a3 = 0.f;
    float a4 = 0.f, a5 = 0.f, a6 = 0.f, a7 = 0.f;
    #pragma unroll 4
    for (int k = 0; k < Dn; ++k) {
        float w = W[k * Dn + c];
        a0 = fmaf(x0[0 * Dn + k], w, a0);
        a1 = fmaf(x0[1 * Dn + k], w, a1);
        a2 = fmaf(x0[2 * Dn + k], w, a2);
        a3 = fmaf(x0[3 * Dn + k], w, a3);
        a4 = fmaf(x0[4 * Dn + k], w, a4);
        a5 = fmaf(x0[5 * Dn + k], w, a5);
        a6 = fmaf(x0[6 * Dn + k], w, a6);
        a7 = fmaf(x0[7 * Dn + k], w, a7);
    }
    xwh[rbase + 0 * Dn + c] = __float2half(a0);
    xwh[rbase + 1 * Dn + c] = __float2half(a1);
    xwh[rbase + 2 * Dn + c] = __float2half(a2);
    xwh[rbase + 3 * Dn + c] = __float2half(a3);
    xwh[rbase + 4 * Dn + c] = __float2half(a4);
    xwh[rbase + 5 * Dn + c] = __float2half(a5);
    xwh[rbase + 6 * Dn + c] = __float2half(a6);
    xwh[rbase + 7 * Dn + c] = __float2half(a7);
}

// ---------------------------------------------------------------------------
// Fused: masked softmax + sparse aggregate of fp16 xw + residual + ELU +
// next-iteration ah1/ah2 (double-buffered). TWO WAVES PER ROW (even/odd
// neighbor parity) -> per-wave serial chain halved, 2x waves for latency
// hiding. Block = 256 threads = 2 rows x 2 waves, all on slot s (XCD
// locality). pn slab is parity-partitioned: gather reads only entries the
// same wave wrote -> no barrier on pn. Two block barriers total (global max
// exchange; acc/sum exchange).
__global__ __launch_bounds__(256) void attn_agg(
        float* __restrict__ x, const __half* __restrict__ xwh,
        const int* __restrict__ adj, const int* __restrict__ deg,
        const float* __restrict__ ah1r, const float* __restrict__ ah2r,
        float* __restrict__ ah1w, float* __restrict__ ah2w,
        const float* __restrict__ gw1, const float* __restrict__ gb1,
        const float* __restrict__ gw2, const float* __restrict__ gb2) {
    int tid  = threadIdx.x;
    int rw   = tid >> 7;               // row within block: 0..1
    int h    = (tid >> 6) & 1;         // neighbor parity for this wave
    int lane = tid & 63;
    int s = blockIdx.x & 7;
    int i = (blockIdx.x >> 3) * 2 + rw;
    int r = s * Nn + i;

    __shared__ float2 pn[2][MAXDEG];   // per-row (p, j); parity-partitioned
    __shared__ float  mx[2][2];        // per-row per-half max
    __shared__ float  sm[2][2];        // per-row per-half exp-sum
    __shared__ float4 xA[2][16];       // wave h=1 acc halves
    __shared__ float4 xB[2][16];

    int d = deg[r]; if (d > MAXDEG) d = MAXDEG;

    // ---- softmax (this wave handles neighbors k = 2*lane + h) ----
    float a1 = ah1r[r];
    const int* al = adj + (size_t)r * MAXDEG;
    const float* ah2s = ah2r + (size_t)s * Nn;
    int k = 2 * lane + h;
    int jn = 0;
    float e = -INFINITY;
    if (k < d) {
        jn = al[k];
        float t = a1 + ah2s[jn];
        e = t > 0.f ? t : 0.2f * t;                // leaky_relu(0.2)
    }
    float m = e;
    #pragma unroll
    for (int o = 32; o > 0; o >>= 1) m = fmaxf(m, __shfl_xor(m, o));
    if (lane == 0) mx[rw][h] = m;
    __syncthreads();
    float M = fmaxf(mx[rw][0], mx[rw][1]);
    float ex = (k < d) ? __expf(e - M) : 0.f;
    float sum = ex;
    #pragma unroll
    for (int o = 32; o > 0; o >>= 1) sum += __shfl_xor(sum, o);
    if (lane == 0) sm[rw][h] = sum;
    pn[rw][k] = make_float2(ex, __int_as_float(jn));   // covers all 128 slots

    // ---- sparse aggregate (own parity only; same-wave LDS, no barrier) ----
    const uint4* xwu = (const uint4*)(xwh + (size_t)s * Nn * Dn);  // 16/row
    int g = lane >> 4;                 // neighbor subgroup 0..3
    int f = lane & 15;                 // feature octet
    float accA[4] = {0.f, 0.f, 0.f, 0.f};
    float accB[4] = {0.f, 0.f, 0.f, 0.f};
    int Mpad = (((d + 1) >> 1) + 15) & ~15;    // per-wave m-count, 16-aligned
    for (int mb = 0; mb < Mpad; mb += 16) {
        float2 q[4];
        uint4  v[4];
        #pragma unroll
        for (int t = 0; t < 4; ++t) q[t] = pn[rw][2 * (mb + 4 * t + g) + h];
        #pragma unroll
        for (int t = 0; t < 4; ++t)
            v[t] = xwu[(size_t)__float_as_int(q[t].y) * 16 + f];
        #pragma unroll
        for (int t = 0; t < 4; ++t) {
            const __half* hh = (const __half*)&v[t];
            float p = q[t].x;
            accA[0] = fmaf(p, __half2float(hh[0]), accA[0]);
            accA[1] = fmaf(p, __half2float(hh[1]), accA[1]);
            accA[2] = fmaf(p, __half2float(hh[2]), accA[2]);
            accA[3] = fmaf(p, __half2float(hh[3]), accA[3]);
            accB[0] = fmaf(p, __half2float(hh[4]), accB[0]);
            accB[1] = fmaf(p, __half2float(hh[5]), accB[1]);
            accB[2] = fmaf(p, __half2float(hh[6]), accB[2]);
            accB[3] = fmaf(p, __half2float(hh[7]), accB[3]);
        }
    }
    // fold the 4 subgroups within this wave
    #pragma unroll
    for (int o = 0; o < 4; ++o) {
        accA[o] += __shfl_xor(accA[o], 16);
        accA[o] += __shfl_xor(accA[o], 32);
        accB[o] += __shfl_xor(accB[o], 16);
        accB[o] += __shfl_xor(accB[o], 32);
    }
    if (h == 1 && lane < 16) {
        xA[rw][lane] = make_float4(accA[0], accA[1], accA[2], accA[3]);
        xB[rw][lane] = make_float4(accB[0], accB[1], accB[2], accB[3]);
    }
    __syncthreads();

    // ---- residual + ELU + store + next-iter ah (wave h=0, lanes 0..15) ----
    if (h == 0 && lane < 16) {
        float4 oA = xA[rw][lane], oB = xB[rw][lane];
        accA[0] += oA.x; accA[1] += oA.y; accA[2] += oA.z; accA[3] += oA.w;
        accB[0] += oB.x; accB[1] += oB.y; accB[2] += oB.z; accB[3] += oB.w;
        float stot = sm[rw][0] + sm[rw][1];
        float inv = (d > 0) ? 1.0f / stot : 0.f;
        float4* x4 = (float4*)(x + (size_t)r * Dn);
        float4 vA4 = x4[2 * lane], vB4 = x4[2 * lane + 1];
        float4 tA, tB, rA, rB;
        tA.x = vA4.x + accA[0] * inv;  tA.y = vA4.y + accA[1] * inv;
        tA.z = vA4.z + accA[2] * inv;  tA.w = vA4.w + accA[3] * inv;
        tB.x = vB4.x + accB[0] * inv;  tB.y = vB4.y + accB[1] * inv;
        tB.z = vB4.z + accB[2] * inv;  tB.w = vB4.w + accB[3] * inv;
        rA.x = tA.x > 0.f ? tA.x : (expf(tA.x) - 1.f);
        rA.y = tA.y > 0.f ? tA.y : (expf(tA.y) - 1.f);
        rA.z = tA.z > 0.f ? tA.z : (expf(tA.z) - 1.f);
        rA.w = tA.w > 0.f ? tA.w : (expf(tA.w) - 1.f);
        rB.x = tB.x > 0.f ? tB.x : (expf(tB.x) - 1.f);
        rB.y = tB.y > 0.f ? tB.y : (expf(tB.y) - 1.f);
        rB.z = tB.z > 0.f ? tB.z : (expf(tB.z) - 1.f);
        rB.w = tB.w > 0.f ? tB.w : (expf(tB.w) - 1.f);
        x4[2 * lane]     = rA;
        x4[2 * lane + 1] = rB;

        // ah for next iteration (row is in rA/rB across lanes 0..15)
        const float4* w14 = (const float4*)gw1;
        const float4* w24 = (const float4*)gw2;
        float4 wa = w14[2 * lane], wb = w14[2 * lane + 1];
        float4 ua = w24[2 * lane], ub = w24[2 * lane + 1];
        float p1 = rA.x * wa.x + rA.y * wa.y + rA.z * wa.z + rA.w * wa.w
                 + rB.x * wb.x + rB.y * wb.y + rB.z * wb.z + rB.w * wb.w;
        float p2 = rA.x * ua.x + rA.y * ua.y + rA.z * ua.z + rA.w * ua.w
                 + rB.x * ub.x + rB.y * ub.y + rB.z * ub.z + rB.w * ub.w;
        #pragma unroll
        for (int o = 8; o >= 1; o >>= 1) {
            p1 += __shfl_xor(p1, o);
            p2 += __shfl_xor(p2, o);
        }
        if (lane == 0) {
            ah1w[r] = p1 + gb1[0];
            ah2w[r] = p2 + gb2[0];
        }
    }
}

// ---------------------------------------------------------------------------
// Stage-1 reduction over rows: 32 chunks of 64 rows per batch, fwd+rev fused.
__global__ void reduce_partial(const float* __restrict__ x, float* __restrict__ part) {
    int b = blockIdx.x >> 5;
    int c = blockIdx.x & 31;
    int tid = threadIdx.x;                     // 0..127 = d
    const float* xf = x + ((size_t)(b * Nn) + c * 64) * Dn;
    const float* xr = x + ((size_t)((4 + b) * Nn) + c * 64) * Dn;
    float sv = 0.f;
    for (int i = 0; i < 64; ++i)
        sv += xf[(size_t)i * Dn + tid] + xr[(size_t)i * Dn + tid];
    part[(size_t)blockIdx.x * Dn + tid] = sv;
}

// ---------------------------------------------------------------------------
// Stage-2: mid[b] = sum of partials; out[b] = mid @ Wout + bout
__global__ void final_out(const float* __restrict__ part,
                          const float* __restrict__ Wout, const float* __restrict__ bout,
                          float* __restrict__ out) {
    int b = blockIdx.x;
    int tid = threadIdx.x;                     // 128 threads
    __shared__ float mid[Dn];
    float sv = 0.f;
    for (int c = 0; c < 32; ++c) sv += part[(size_t)(b * 32 + c) * Dn + tid];
    mid[tid] = sv;
    __syncthreads();
    if (tid < OUTn) {
        float o = bout[tid];
        #pragma unroll 4
        for (int k = 0; k < Dn; ++k) o = fmaf(mid[k], Wout[k * OUTn + tid], o);
        out[b * OUTn + tid] = o;
    }
}

// ---------------------------------------------------------------------------
extern "C" void kernel_launch(void* const* d_in, const int* in_sizes, int n_in,
                              void* d_out, int out_size, void* d_ws, size_t ws_size,
                              hipStream_t stream) {
    const float* INPUT = (const float*)d_in[0];
    const float* CFG   = (const float*)d_in[1];
    // d_in[2] = LFG, unused by the forward pass
    const float* w1    = (const float*)d_in[3];
    const float* b1    = (const float*)d_in[4];
    const float* w2    = (const float*)d_in[5];
    const float* b2    = (const float*)d_in[6];
    const float* Wm    = (const float*)d_in[7];
    const float* Wout  = (const float*)d_in[8];
    const float* bout  = (const float*)d_in[9];
    float* out = (float*)d_out;

    // workspace layout (~22.6 MB)
    float*  x    = (float*)d_ws;                          // Sn*Nn*Dn   (8 MB)
    __half* xwh  = (__half*)(x + (size_t)Sn * Nn * Dn);   // Sn*Nn*Dn   (4 MB)
    int*    adj  = (int*)(xwh + (size_t)Sn * Nn * Dn);    // Sn*Nn*MAXDEG (8 MB)
    int*    deg  = adj + (size_t)Sn * Nn * MAXDEG;        // Sn*Nn
    float*  ah1a = (float*)(deg + Sn * Nn);               // Sn*Nn
    float*  ah2a = ah1a + Sn * Nn;                        // Sn*Nn
    float*  ah1b = ah2a + Sn * Nn;                        // Sn*Nn
    float*  ah2b = ah1b + Sn * Nn;                        // Sn*Nn
    float*  part = ah2b + Sn * Nn;                        // Bn*32*Dn
    unsigned long long* bits = (unsigned long long*)(part + Bn * 32 * Dn); // 2 MB

    fwd_bits_init<<<(Bn * Nn) / 4 + (Bn * Nn) / 8, 256, 0, stream>>>(
        (const float4*)CFG, bits, adj, deg, (const float4*)INPUT, (float4*)x,
        w1, b1, w2, b2, ah1a, ah2a);

    for (int it = 0; it < NITER; ++it) {
        if (it == 0) {
            gemm_rev<<<(Sn * Nn) / 8 + (Bn * Nn) / 2, 128, 0, stream>>>(
                x, Wm, xwh, bits, adj, deg);
        } else {
            gemm_xw<<<(Sn * Nn) / 8, 128, 0, stream>>>(x, Wm, xwh);
        }
        const float* r1 = (it & 1) ? ah1b : ah1a;
        const float* r2 = (it & 1) ? ah2b : ah2a;
        float* w1p = (it & 1) ? ah1a : ah1b;
        float* w2p = (it & 1) ? ah2a : ah2b;
        attn_agg<<<(Sn * Nn) / 2, 256, 0, stream>>>(
            x, xwh, adj, deg, r1, r2, w1p, w2p, w1, b1, w2, b2);
    }

    reduce_partial<<<Bn * 32, 128, 0, stream>>>(x, part);
    final_out     <<<Bn, 128, 0, stream>>>(part, Wout, bout, out);
}

// Round 12
// 167.141 us; speedup vs baseline: 1.7255x; 1.1244x over previous
//
#include <hip/hip_runtime.h>
#include <hip/hip_fp16.h>
#include <cstdint>
#include <cstddef>

// Problem constants (match reference)
#define Bn 4
#define Nn 2048
#define Dn 128
#define OUTn 64
#define Sn 8          // 4 batches x {fwd, rev}
#define MAXDEG 128    // binomial(2048, 1/32): mean 64, sd 7.9; max over 16K rows ~99
#define NITER 3

// ---------------------------------------------------------------------------
// deposit low 16 bits of x at bit positions 0,4,8,...,60
__device__ __forceinline__ unsigned long long spread4(unsigned long long x) {
    x &= 0xFFFFull;
    x = (x | (x << 24)) & 0x000000FF000000FFull;
    x = (x | (x << 12)) & 0x000F000F000F000Full;
    x = (x | (x << 6))  & 0x0303030303030303ull;
    x = (x | (x << 3))  & 0x1111111111111111ull;
    return x;
}

// ---------------------------------------------------------------------------
// Blocks [0, 4096): one wave per forward row (b,i): forward adjacency
// (sorted, deterministic), degree, and the column-major bitmask.
// Blocks [4096, 5120): row-organized init: x[s]=relu(INPUT[b]) for s=b,b+4
// AND the iteration-0 attention scalars ah1/ah2 (32-lane shfl reduce).
__global__ void fwd_bits_init(const float4* __restrict__ cfg4,
                              unsigned long long* __restrict__ bits,
                              int* __restrict__ adj, int* __restrict__ deg,
                              const float4* __restrict__ in4, float4* __restrict__ x4,
                              const float* __restrict__ w1, const float* __restrict__ b1,
                              const float* __restrict__ w2, const float* __restrict__ b2,
                              float* __restrict__ ah1, float* __restrict__ ah2) {
    if (blockIdx.x >= (Bn * Nn) / 4) {
        int blk = blockIdx.x - (Bn * Nn) / 4;         // 0..1023
        int t = threadIdx.x;
        int row = blk * 8 + (t >> 5);                 // [0, Bn*Nn)
        int q   = t & 31;                             // feature quad
        float4 v = in4[(size_t)row * 32 + q];
        v.x = v.x > 0.f ? v.x : 0.f;
        v.y = v.y > 0.f ? v.y : 0.f;
        v.z = v.z > 0.f ? v.z : 0.f;
        v.w = v.w > 0.f ? v.w : 0.f;
        x4[(size_t)row * 32 + q] = v;
        x4[(size_t)(Bn * Nn * Dn) / 4 + (size_t)row * 32 + q] = v;
        const float4* w14 = (const float4*)w1;
        const float4* w24 = (const float4*)w2;
        float4 wa = w14[q], wb = w24[q];
        float p1 = v.x * wa.x + v.y * wa.y + v.z * wa.z + v.w * wa.w;
        float p2 = v.x * wb.x + v.y * wb.y + v.z * wb.z + v.w * wb.w;
        #pragma unroll
        for (int o = 16; o >= 1; o >>= 1) {
            p1 += __shfl_xor(p1, o);
            p2 += __shfl_xor(p2, o);
        }
        if (q == 0) {
            float a1 = p1 + b1[0], a2 = p2 + b2[0];
            ah1[row] = a1; ah1[Bn * Nn + row] = a1;   // fwd slot b, rev slot 4+b
            ah2[row] = a2; ah2[Bn * Nn + row] = a2;
        }
        return;
    }
    int row  = blockIdx.x * 4 + (threadIdx.x >> 6);   // [0, Bn*Nn)
    int lane = threadIdx.x & 63;
    int b = row >> 11;
    int i = row & (Nn - 1);
    const float4* crow = cfg4 + (size_t)row * (Nn / 4);
    int* dst = adj + (size_t)row * MAXDEG;
    int cnt = 0;
    for (int j0 = 0; j0 < Nn; j0 += 256) {
        float4 v = crow[(j0 >> 2) + lane];
        int nib = (v.x != 0.f) | ((v.y != 0.f) << 1) |
                  ((v.z != 0.f) << 2) | ((v.w != 0.f) << 3);
        unsigned long long m0 = __ballot(nib & 1);
        unsigned long long m1 = __ballot(nib & 2);
        unsigned long long m2 = __ballot(nib & 4);
        unsigned long long m3 = __ballot(nib & 8);
        unsigned long long below = (1ull << lane) - 1ull;
        int off = __popcll(m0 & below) + __popcll(m1 & below) +
                  __popcll(m2 & below) + __popcll(m3 & below);
        int total = __popcll(m0) + __popcll(m1) + __popcll(m2) + __popcll(m3);
        int base = cnt + off;
        int col = j0 + 4 * lane;
        if (nib & 1) { if (base < MAXDEG) dst[base] = col;     base++; }
        if (nib & 2) { if (base < MAXDEG) dst[base] = col + 1; base++; }
        if (nib & 4) { if (base < MAXDEG) dst[base] = col + 2; base++; }
        if (nib & 8) { if (base < MAXDEG) dst[base] = col + 3; base++; }
        if (lane < 4) {
            int sh = lane << 4;
            unsigned long long w = spread4(m0 >> sh) | (spread4(m1 >> sh) << 1) |
                                   (spread4(m2 >> sh) << 2) | (spread4(m3 >> sh) << 3);
            int jw = (j0 >> 6) + lane;
            bits[((size_t)(b * 32 + jw)) * Nn + i] = w;
        }
        cnt += total;
    }
    if (lane == 0) deg[row] = (cnt < MAXDEG ? cnt : MAXDEG);
}

// ---------------------------------------------------------------------------
// Merged launch (both depend only on fwd_bits_init; disjoint outputs):
// Blocks [0, 2048):    xw = fp16(x @ W) for iteration 0 (8 rows/block).
// Blocks [2048, 6144): reverse adjacency: 2 waves/block, one reverse row
// each; read plane bits[b][j>>6][*] contiguously (L1-resident across 64
// consecutive rows); ballot-compact ascending i. Deterministic and sorted.
__global__ void gemm_rev(const float* __restrict__ x, const float* __restrict__ W,
                         __half* __restrict__ xwh,
                         const unsigned long long* __restrict__ bits,
                         int* __restrict__ adj, int* __restrict__ deg) {
    if (blockIdx.x < (Sn * Nn) / 8) {
        int c = threadIdx.x;                              // column 0..127
        size_t rbase = (size_t)blockIdx.x * 8 * Dn;
        const float* x0 = x + rbase;
        float a0 = 0.f, a1 = 0.f, a2 = 0.f, a3 = 0.f;
        float a4 = 0.f, a5 = 0.f, a6 = 0.f, a7 = 0.f;
        #pragma unroll 4
        for (int k = 0; k < Dn; ++k) {
            float w = W[k * Dn + c];
            a0 = fmaf(x0[0 * Dn + k], w, a0);
            a1 = fmaf(x0[1 * Dn + k], w, a1);
            a2 = fmaf(x0[2 * Dn + k], w, a2);
            a3 = fmaf(x0[3 * Dn + k], w, a3);
            a4 = fmaf(x0[4 * Dn + k], w, a4);
            a5 = fmaf(x0[5 * Dn + k], w, a5);
            a6 = fmaf(x0[6 * Dn + k], w, a6);
            a7 = fmaf(x0[7 * Dn + k], w, a7);
        }
        xwh[rbase + 0 * Dn + c] = __float2half(a0);
        xwh[rbase + 1 * Dn + c] = __float2half(a1);
        xwh[rbase + 2 * Dn + c] = __float2half(a2);
        xwh[rbase + 3 * Dn + c] = __float2half(a3);
        xwh[rbase + 4 * Dn + c] = __float2half(a4);
        xwh[rbase + 5 * Dn + c] = __float2half(a5);
        xwh[rbase + 6 * Dn + c] = __float2half(a6);
        xwh[rbase + 7 * Dn + c] = __float2half(a7);
        return;
    }
    int r    = (blockIdx.x - (Sn * Nn) / 8) * 2 + (threadIdx.x >> 6);  // [0, Bn*Nn)
    int lane = threadIdx.x & 63;
    int b = r >> 11;
    int j = r & (Nn - 1);
    const unsigned long long* col = bits + ((size_t)(b * 32 + (j >> 6))) * Nn;
    int bit = j & 63;
    int out_r = (Bn + b) * Nn + j;
    int* dst = adj + (size_t)out_r * MAXDEG;
    int cnt = 0;
    for (int i0 = 0; i0 < Nn; i0 += 64) {
        unsigned long long word = col[i0 + lane];
        bool e = (word >> bit) & 1;
        unsigned long long m = __ballot(e);
        if (e) {
            int pos = cnt + __popcll(m & ((1ull << lane) - 1ull));
            if (pos < MAXDEG) dst[pos] = i0 + lane;
        }
        cnt += __popcll(m);
    }
    if (lane == 0) deg[out_r] = (cnt < MAXDEG ? cnt : MAXDEG);
}

// ---------------------------------------------------------------------------
// Pure streaming GEMM: xw = fp16(x @ W). 8 rows per 128-thread block (used
// for iterations 1..NITER-1).
__global__ void gemm_xw(const float* __restrict__ x, const float* __restrict__ W,
                        __half* __restrict__ xwh) {
    int c = threadIdx.x;                              // column 0..127
    size_t rbase = (size_t)blockIdx.x * 8 * Dn;
    const float* x0 = x + rbase;
    float a0 = 0.f, a1 = 0.f, a2 = 0.f, a3 = 0.f;
    float a4 = 0.f, a5 = 0.f, a6 = 0.f, a7 = 0.f;
    #pragma unroll 4
    for (int k = 0; k < Dn; ++k) {
        float w = W[k * Dn + c];
        a0 = fmaf(x0[0 * Dn + k], w, a0);
        a1 = fmaf(x0[1 * Dn + k], w, a1);
        a2 = fmaf(x0[2 * Dn + k], w, a2);
        a3 = fmaf(x0[3 * Dn + k], w, a3);
        a4 = fmaf(x0[4 * Dn + k], w, a4);
        a5 = fmaf(x0[5 * Dn + k], w, a5);
        a6 = fmaf(x0[6 * Dn + k], w, a6);
        a7 = fmaf(x0[7 * Dn + k], w, a7);
    }
    xwh[rbase + 0 * Dn + c] = __float2half(a0);
    xwh[rbase + 1 * Dn + c] = __float2half(a1);
    xwh[rbase + 2 * Dn + c] = __float2half(a2);
    xwh[rbase + 3 * Dn + c] = __float2half(a3);
    xwh[rbase + 4 * Dn + c] = __float2half(a4);
    xwh[rbase + 5 * Dn + c] = __float2half(a5);
    xwh[rbase + 6 * Dn + c] = __float2half(a6);
    xwh[rbase + 7 * Dn + c] = __float2half(a7);
}

// ---------------------------------------------------------------------------
// Fused: masked softmax + sparse aggregate of fp16 xw + residual + ELU +
// next-iteration ah1/ah2 (double-buffered). ONE WAVE PER ROW, no barriers
// (R8 geometry — simplest proven structure). Gather MACs use __hfma2
// (v_pk_fma_f16): 16 packed FMAs per lane per 16-neighbor chunk instead of
// 32 cvt + 32 fma — gather VALU issue cut 2.5-4x. Accumulators are fp16
// pairs; converted to fp32 before the cross-group shfl folds.
__global__ __launch_bounds__(256) void attn_agg(
        float* __restrict__ x, const __half* __restrict__ xwh,
        const int* __restrict__ adj, const int* __restrict__ deg,
        const float* __restrict__ ah1r, const float* __restrict__ ah2r,
        float* __restrict__ ah1w, float* __restrict__ ah2w,
        const float* __restrict__ gw1, const float* __restrict__ gb1,
        const float* __restrict__ gw2, const float* __restrict__ gb2) {
    int w    = threadIdx.x >> 6;       // wave 0..3
    int lane = threadIdx.x & 63;
    int s = blockIdx.x & 7;
    int i = (blockIdx.x >> 3) * 4 + w;
    int r = s * Nn + i;

    __shared__ float2 pn[4][MAXDEG];   // per-wave (p, j) slab

    int d = deg[r]; if (d > MAXDEG) d = MAXDEG;

    // ---- softmax over neighbor list (this wave, 64 lanes) ----
    float a1 = ah1r[r];
    const int* al = adj + (size_t)r * MAXDEG;
    const float* ah2s = ah2r + (size_t)s * Nn;
    int jlo = 0, jhi = 0;
    float elo = -INFINITY, ehi = -INFINITY;
    if (lane < d) {
        jlo = al[lane];
        float e = a1 + ah2s[jlo];
        elo = e > 0.f ? e : 0.2f * e;              // leaky_relu(0.2)
    }
    if (lane + 64 < d) {
        jhi = al[lane + 64];
        float e = a1 + ah2s[jhi];
        ehi = e > 0.f ? e : 0.2f * e;
    }
    float m = fmaxf(elo, ehi);
    #pragma unroll
    for (int o = 32; o > 0; o >>= 1) m = fmaxf(m, __shfl_xor(m, o));
    float exlo = (lane < d)      ? __expf(elo - m) : 0.f;
    float exhi = (lane + 64 < d) ? __expf(ehi - m) : 0.f;
    float sum = exlo + exhi;
    #pragma unroll
    for (int o = 32; o > 0; o >>= 1) sum += __shfl_xor(sum, o);
    float inv = (d > 0) ? 1.0f / sum : 0.f;

    // publish (p, j) — all 128 entries written (zero-padded past d)
    pn[w][lane]      = make_float2(exlo, __int_as_float(jlo));
    pn[w][lane + 64] = make_float2(exhi, __int_as_float(jhi));
    // no __syncthreads: same-wave LDS write->read, compiler emits lgkmcnt

    // ---- sparse aggregate: group g = lane>>4 handles neighbors k = 4t+g;
    //      lane f = lane&15 owns features 8f..8f+7 (one uint4 of fp16) ----
    const uint4* xwu = (const uint4*)(xwh + (size_t)s * Nn * Dn);  // 16/row
    int g = lane >> 4;
    int f = lane & 15;
    __half2 acc2[4];
    #pragma unroll
    for (int e = 0; e < 4; ++e) acc2[e] = __halves2half2(__float2half(0.f), __float2half(0.f));
    int dpad = (d + 15) & ~15;
    for (int base = 0; base < dpad; base += 16) {
        float2 q[4];
        uint4  v[4];
        #pragma unroll
        for (int t = 0; t < 4; ++t) q[t] = pn[w][base + 4 * t + g];
        #pragma unroll
        for (int t = 0; t < 4; ++t)
            v[t] = xwu[(size_t)__float_as_int(q[t].y) * 16 + f];
        #pragma unroll
        for (int t = 0; t < 4; ++t) {
            __half   ph = __float2half(q[t].x);
            __half2  p2 = __halves2half2(ph, ph);
            const __half2* hh = (const __half2*)&v[t];
            acc2[0] = __hfma2(p2, hh[0], acc2[0]);
            acc2[1] = __hfma2(p2, hh[1], acc2[1]);
            acc2[2] = __hfma2(p2, hh[2], acc2[2]);
            acc2[3] = __hfma2(p2, hh[3], acc2[3]);
        }
    }
    // convert to fp32, then fold the 4 groups across lanes
    float2 f0 = __half22float2(acc2[0]);
    float2 f1 = __half22float2(acc2[1]);
    float2 f2 = __half22float2(acc2[2]);
    float2 f3 = __half22float2(acc2[3]);
    float accA[4] = { f0.x, f0.y, f1.x, f1.y };
    float accB[4] = { f2.x, f2.y, f3.x, f3.y };
    #pragma unroll
    for (int e = 0; e < 4; ++e) {
        accA[e] += __shfl_xor(accA[e], 16);
        accA[e] += __shfl_xor(accA[e], 32);
        accB[e] += __shfl_xor(accB[e], 16);
        accB[e] += __shfl_xor(accB[e], 32);
    }

    // ---- residual + ELU + store + next-iter ah (lanes 0..15) ----
    if (lane < 16) {
        float4* x4 = (float4*)(x + (size_t)r * Dn);
        float4 vA4 = x4[2 * lane], vB4 = x4[2 * lane + 1];
        float4 tA, tB, rA, rB;
        tA.x = vA4.x + accA[0] * inv;  tA.y = vA4.y + accA[1] * inv;
        tA.z = vA4.z + accA[2] * inv;  tA.w = vA4.w + accA[3] * inv;
        tB.x = vB4.x + accB[0] * inv;  tB.y = vB4.y + accB[1] * inv;
        tB.z = vB4.z + accB[2] * inv;  tB.w = vB4.w + accB[3] * inv;
        rA.x = tA.x > 0.f ? tA.x : (expf(tA.x) - 1.f);
        rA.y = tA.y > 0.f ? tA.y : (expf(tA.y) - 1.f);
        rA.z = tA.z > 0.f ? tA.z : (expf(tA.z) - 1.f);
        rA.w = tA.w > 0.f ? tA.w : (expf(tA.w) - 1.f);
        rB.x = tB.x > 0.f ? tB.x : (expf(tB.x) - 1.f);
        rB.y = tB.y > 0.f ? tB.y : (expf(tB.y) - 1.f);
        rB.z = tB.z > 0.f ? tB.z : (expf(tB.z) - 1.f);
        rB.w = tB.w > 0.f ? tB.w : (expf(tB.w) - 1.f);
        x4[2 * lane]     = rA;
        x4[2 * lane + 1] = rB;

        // ah for next iteration (row is in rA/rB across lanes 0..15)
        const float4* w14 = (const float4*)gw1;
        const float4* w24 = (const float4*)gw2;
        float4 wa = w14[2 * lane], wb = w14[2 * lane + 1];
        float4 ua = w24[2 * lane], ub = w24[2 * lane + 1];
        float p1 = rA.x * wa.x + rA.y * wa.y + rA.z * wa.z + rA.w * wa.w
                 + rB.x * wb.x + rB.y * wb.y + rB.z * wb.z + rB.w * wb.w;
        float p2 = rA.x * ua.x + rA.y * ua.y + rA.z * ua.z + rA.w * ua.w
                 + rB.x * ub.x + rB.y * ub.y + rB.z * ub.z + rB.w * ub.w;
        #pragma unroll
        for (int o = 8; o >= 1; o >>= 1) {
            p1 += __shfl_xor(p1, o);
            p2 += __shfl_xor(p2, o);
        }
        if (lane == 0) {
            ah1w[r] = p1 + gb1[0];
            ah2w[r] = p2 + gb2[0];
        }
    }
}

// ---------------------------------------------------------------------------
// Stage-1 reduction over rows: 32 chunks of 64 rows per batch, fwd+rev fused.
__global__ void reduce_partial(const float* __restrict__ x, float* __restrict__ part) {
    int b = blockIdx.x >> 5;
    int c = blockIdx.x & 31;
    int tid = threadIdx.x;                     // 0..127 = d
    const float* xf = x + ((size_t)(b * Nn) + c * 64) * Dn;
    const float* xr = x + ((size_t)((4 + b) * Nn) + c * 64) * Dn;
    float sv = 0.f;
    for (int i = 0; i < 64; ++i)
        sv += xf[(size_t)i * Dn + tid] + xr[(size_t)i * Dn + tid];
    part[(size_t)blockIdx.x * Dn + tid] = sv;
}

// ---------------------------------------------------------------------------
// Stage-2: mid[b] = sum of partials; out[b] = mid @ Wout + bout
__global__ void final_out(const float* __restrict__ part,
                          const float* __restrict__ Wout, const float* __restrict__ bout,
                          float* __restrict__ out) {
    int b = blockIdx.x;
    int tid = threadIdx.x;                     // 128 threads
    __shared__ float mid[Dn];
    float sv = 0.f;
    for (int c = 0; c < 32; ++c) sv += part[(size_t)(b * 32 + c) * Dn + tid];
    mid[tid] = sv;
    __syncthreads();
    if (tid < OUTn) {
        float o = bout[tid];
        #pragma unroll 4
        for (int k = 0; k < Dn; ++k) o = fmaf(mid[k], Wout[k * OUTn + tid], o);
        out[b * OUTn + tid] = o;
    }
}

// ---------------------------------------------------------------------------
extern "C" void kernel_launch(void* const* d_in, const int* in_sizes, int n_in,
                              void* d_out, int out_size, void* d_ws, size_t ws_size,
                              hipStream_t stream) {
    const float* INPUT = (const float*)d_in[0];
    const float* CFG   = (const float*)d_in[1];
    // d_in[2] = LFG, unused by the forward pass
    const float* w1    = (const float*)d_in[3];
    const float* b1    = (const float*)d_in[4];
    const float* w2    = (const float*)d_in[5];
    const float* b2    = (const float*)d_in[6];
    const float* Wm    = (const float*)d_in[7];
    const float* Wout  = (const float*)d_in[8];
    const float* bout  = (const float*)d_in[9];
    float* out = (float*)d_out;

    // workspace layout (~22.6 MB)
    float*  x    = (float*)d_ws;                          // Sn*Nn*Dn   (8 MB)
    __half* xwh  = (__half*)(x + (size_t)Sn * Nn * Dn);   // Sn*Nn*Dn   (4 MB)
    int*    adj  = (int*)(xwh + (size_t)Sn * Nn * Dn);    // Sn*Nn*MAXDEG (8 MB)
    int*    deg  = adj + (size_t)Sn * Nn * MAXDEG;        // Sn*Nn
    float*  ah1a = (float*)(deg + Sn * Nn);               // Sn*Nn
    float*  ah2a = ah1a + Sn * Nn;                        // Sn*Nn
    float*  ah1b = ah2a + Sn * Nn;                        // Sn*Nn
    float*  ah2b = ah1b + Sn * Nn;                        // Sn*Nn
    float*  part = ah2b + Sn * Nn;                        // Bn*32*Dn
    unsigned long long* bits = (unsigned long long*)(part + Bn * 32 * Dn); // 2 MB

    fwd_bits_init<<<(Bn * Nn) / 4 + (Bn * Nn) / 8, 256, 0, stream>>>(
        (const float4*)CFG, bits, adj, deg, (const float4*)INPUT, (float4*)x,
        w1, b1, w2, b2, ah1a, ah2a);

    for (int it = 0; it < NITER; ++it) {
        if (it == 0) {
            gemm_rev<<<(Sn * Nn) / 8 + (Bn * Nn) / 2, 128, 0, stream>>>(
                x, Wm, xwh, bits, adj, deg);
        } else {
            gemm_xw<<<(Sn * Nn) / 8, 128, 0, stream>>>(x, Wm, xwh);
        }
        const float* r1 = (it & 1) ? ah1b : ah1a;
        const float* r2 = (it & 1) ? ah2b : ah2a;
        float* w1p = (it & 1) ? ah1a : ah1b;
        float* w2p = (it & 1) ? ah2a : ah2b;
        attn_agg<<<(Sn * Nn) / 4, 256, 0, stream>>>(
            x, xwh, adj, deg, r1, r2, w1p, w2p, w1, b1, w2, b2);
    }

    reduce_partial<<<Bn * 32, 128, 0, stream>>>(x, part);
    final_out     <<<Bn, 128, 0, stream>>>(part, Wout, bout, out);
}

// Round 14
// 141.015 us; speedup vs baseline: 2.0452x; 1.1853x over previous
//
#include <hip/hip_runtime.h>
#include <hip/hip_fp16.h>
#include <cstdint>
#include <cstddef>

// Problem constants (match reference)
#define Bn 4
#define Nn 2048
#define Dn 128
#define OUTn 64
#define Sn 8          // 4 batches x {fwd, rev}
#define MAXDEG 128    // binomial(2048, 1/32): mean 64, sd 7.9; max over 16K rows ~99
#define NITER 3

typedef _Float16 half8 __attribute__((ext_vector_type(8)));
typedef float floatx4 __attribute__((ext_vector_type(4)));

// ---------------------------------------------------------------------------
// deposit low 16 bits of x at bit positions 0,4,8,...,60
__device__ __forceinline__ unsigned long long spread4(unsigned long long x) {
    x &= 0xFFFFull;
    x = (x | (x << 24)) & 0x000000FF000000FFull;
    x = (x | (x << 12)) & 0x000F000F000F000Full;
    x = (x | (x << 6))  & 0x0303030303030303ull;
    x = (x | (x << 3))  & 0x1111111111111111ull;
    return x;
}

// ---------------------------------------------------------------------------
// Blocks [0, 4096): one wave per forward row (b,i): forward adjacency
// (sorted, deterministic), degree, and the column-major bitmask.
// Blocks [4096, 5120): row-organized init: x/xh = relu(INPUT[b]) for slots
// b and b+4, AND the iteration-0 attention scalars ah1/ah2.
// Block 5120: WhT[c][k] = fp16(W[k][c])  (one-time transpose+convert).
__global__ void fwd_bits_init(const float4* __restrict__ cfg4,
                              unsigned long long* __restrict__ bits,
                              int* __restrict__ adj, int* __restrict__ deg,
                              const float4* __restrict__ in4, float4* __restrict__ x4,
                              __half* __restrict__ xh,
                              const float* __restrict__ W, __half* __restrict__ WhT,
                              const float* __restrict__ w1, const float* __restrict__ b1,
                              const float* __restrict__ w2, const float* __restrict__ b2,
                              float* __restrict__ ah1, float* __restrict__ ah2) {
    if (blockIdx.x >= (Bn * Nn) / 4 + (Bn * Nn) / 8) {
        // W transpose+convert: 128 active threads, k-major coalesced reads
        int t = threadIdx.x;
        if (t < Dn) {
            for (int k = 0; k < Dn; ++k)
                WhT[(size_t)t * Dn + k] = __float2half(W[(size_t)k * Dn + t]);
        }
        return;
    }
    if (blockIdx.x >= (Bn * Nn) / 4) {
        int blk = blockIdx.x - (Bn * Nn) / 4;         // 0..1023
        int t = threadIdx.x;
        int row = blk * 8 + (t >> 5);                 // [0, Bn*Nn)
        int q   = t & 31;                             // feature quad
        float4 v = in4[(size_t)row * 32 + q];
        v.x = v.x > 0.f ? v.x : 0.f;
        v.y = v.y > 0.f ? v.y : 0.f;
        v.z = v.z > 0.f ? v.z : 0.f;
        v.w = v.w > 0.f ? v.w : 0.f;
        x4[(size_t)row * 32 + q] = v;
        x4[(size_t)(Bn * Nn * Dn) / 4 + (size_t)row * 32 + q] = v;
        __half2 p0h = __floats2half2_rn(v.x, v.y);
        __half2 p1h = __floats2half2_rn(v.z, v.w);
        uint2 u2;
        u2.x = *(unsigned*)&p0h; u2.y = *(unsigned*)&p1h;
        ((uint2*)xh)[(size_t)row * 32 + q] = u2;
        ((uint2*)xh)[(size_t)(Bn * Nn) * 32 + (size_t)row * 32 + q] = u2;
        const float4* w14 = (const float4*)w1;
        const float4* w24 = (const float4*)w2;
        float4 wa = w14[q], wb = w24[q];
        float p1 = v.x * wa.x + v.y * wa.y + v.z * wa.z + v.w * wa.w;
        float p2 = v.x * wb.x + v.y * wb.y + v.z * wb.z + v.w * wb.w;
        #pragma unroll
        for (int o = 16; o >= 1; o >>= 1) {
            p1 += __shfl_xor(p1, o);
            p2 += __shfl_xor(p2, o);
        }
        if (q == 0) {
            float a1 = p1 + b1[0], a2 = p2 + b2[0];
            ah1[row] = a1; ah1[Bn * Nn + row] = a1;   // fwd slot b, rev slot 4+b
            ah2[row] = a2; ah2[Bn * Nn + row] = a2;
        }
        return;
    }
    int row  = blockIdx.x * 4 + (threadIdx.x >> 6);   // [0, Bn*Nn)
    int lane = threadIdx.x & 63;
    int b = row >> 11;
    int i = row & (Nn - 1);
    const float4* crow = cfg4 + (size_t)row * (Nn / 4);
    int* dst = adj + (size_t)row * MAXDEG;
    int cnt = 0;
    for (int j0 = 0; j0 < Nn; j0 += 256) {
        float4 v = crow[(j0 >> 2) + lane];
        int nib = (v.x != 0.f) | ((v.y != 0.f) << 1) |
                  ((v.z != 0.f) << 2) | ((v.w != 0.f) << 3);
        unsigned long long m0 = __ballot(nib & 1);
        unsigned long long m1 = __ballot(nib & 2);
        unsigned long long m2 = __ballot(nib & 4);
        unsigned long long m3 = __ballot(nib & 8);
        unsigned long long below = (1ull << lane) - 1ull;
        int off = __popcll(m0 & below) + __popcll(m1 & below) +
                  __popcll(m2 & below) + __popcll(m3 & below);
        int total = __popcll(m0) + __popcll(m1) + __popcll(m2) + __popcll(m3);
        int base = cnt + off;
        int col = j0 + 4 * lane;
        if (nib & 1) { if (base < MAXDEG) dst[base] = col;     base++; }
        if (nib & 2) { if (base < MAXDEG) dst[base] = col + 1; base++; }
        if (nib & 4) { if (base < MAXDEG) dst[base] = col + 2; base++; }
        if (nib & 8) { if (base < MAXDEG) dst[base] = col + 3; base++; }
        if (lane < 4) {
            int sh = lane << 4;
            unsigned long long w = spread4(m0 >> sh) | (spread4(m1 >> sh) << 1) |
                                   (spread4(m2 >> sh) << 2) | (spread4(m3 >> sh) << 3);
            int jw = (j0 >> 6) + lane;
            bits[((size_t)(b * 32 + jw)) * Nn + i] = w;
        }
        cnt += total;
    }
    if (lane == 0) deg[row] = (cnt < MAXDEG ? cnt : MAXDEG);
}

// ---------------------------------------------------------------------------
// MFMA gemm tile: one wave computes one 16x16 output tile of xw = xh @ W
// over K=128 via 4x mfma_f32_16x16x32_f16. Fragment layout per learn_hip
// m92/m97 (A,B: lane m/n = l&15, k = 8*(l>>4)+e, 16B contiguous loads from
// row-major xh / WhT) and m89 (C/D: col = l&15, row = 4*(l>>4)+reg).
__device__ __forceinline__ void gemm_tile_mfma(const __half* __restrict__ xh,
                                               const __half* __restrict__ WhT,
                                               __half* __restrict__ xwh, int tile) {
    int lane = threadIdx.x & 63;
    int rowTile = tile >> 3, colTile = tile & 7;
    int mn = lane & 15, kseg = lane >> 4;
    const uint4* Arow = (const uint4*)(xh + ((size_t)(rowTile * 16 + mn)) * Dn);
    const uint4* Brow = (const uint4*)(WhT + ((size_t)(colTile * 16 + mn)) * Dn);
    floatx4 c = {0.f, 0.f, 0.f, 0.f};
    #pragma unroll
    for (int ks = 0; ks < 4; ++ks) {
        uint4 au = Arow[ks * 4 + kseg];    // k0 = ks*32 + kseg*8
        uint4 bu = Brow[ks * 4 + kseg];
        half8 a = *(half8*)&au;
        half8 b = *(half8*)&bu;
        c = __builtin_amdgcn_mfma_f32_16x16x32_f16(a, b, c, 0, 0, 0);
    }
    int row = (lane >> 4) * 4;
    __half* dst = xwh + ((size_t)(rowTile * 16 + row)) * Dn + colTile * 16 + mn;
    #pragma unroll
    for (int rg = 0; rg < 4; ++rg)
        dst[(size_t)rg * Dn] = __float2half(c[rg]);
}

// ---------------------------------------------------------------------------
// it=0 merged launch: blocks [0,2048) = MFMA gemm (4 tiles/block);
// blocks [2048, 4096): reverse adjacency, 4 waves x 1 reverse row each
// (2048 blocks x 4 = all 8192 reverse rows):
// read plane bits[b][j>>6][*] contiguously; ballot-compact ascending i.
__global__ void gemm_rev(const __half* __restrict__ xh, const __half* __restrict__ WhT,
                         __half* __restrict__ xwh,
                         const unsigned long long* __restrict__ bits,
                         int* __restrict__ adj, int* __restrict__ deg) {
    if (blockIdx.x < 2048) {
        gemm_tile_mfma(xh, WhT, xwh, blockIdx.x * 4 + (threadIdx.x >> 6));
        return;
    }
    int r    = (blockIdx.x - 2048) * 4 + (threadIdx.x >> 6);  // [0, Bn*Nn)
    int lane = threadIdx.x & 63;
    int b = r >> 11;
    int j = r & (Nn - 1);
    const unsigned long long* col = bits + ((size_t)(b * 32 + (j >> 6))) * Nn;
    int bit = j & 63;
    int out_r = (Bn + b) * Nn + j;
    int* dst = adj + (size_t)out_r * MAXDEG;
    int cnt = 0;
    for (int i0 = 0; i0 < Nn; i0 += 64) {
        unsigned long long word = col[i0 + lane];
        bool e = (word >> bit) & 1;
        unsigned long long m = __ballot(e);
        if (e) {
            int pos = cnt + __popcll(m & ((1ull << lane) - 1ull));
            if (pos < MAXDEG) dst[pos] = i0 + lane;
        }
        cnt += __popcll(m);
    }
    if (lane == 0) deg[out_r] = (cnt < MAXDEG ? cnt : MAXDEG);
}

// ---------------------------------------------------------------------------
// Standalone MFMA gemm (iterations 1..NITER-1): 2048 blocks x 4 tiles.
__global__ void gemm_mfma(const __half* __restrict__ xh, const __half* __restrict__ WhT,
                          __half* __restrict__ xwh) {
    gemm_tile_mfma(xh, WhT, xwh, blockIdx.x * 4 + (threadIdx.x >> 6));
}

// ---------------------------------------------------------------------------
// Fused: masked softmax + sparse aggregate of fp16 xw (__hfma2 packed MACs)
// + residual + ELU + fp16 x-mirror write + next-iteration ah1/ah2 (double-
// buffered). ONE WAVE PER ROW, no barriers (R8/R12 geometry).
__global__ __launch_bounds__(256) void attn_agg(
        float* __restrict__ x, __half* __restrict__ xh,
        const __half* __restrict__ xwh,
        const int* __restrict__ adj, const int* __restrict__ deg,
        const float* __restrict__ ah1r, const float* __restrict__ ah2r,
        float* __restrict__ ah1w, float* __restrict__ ah2w,
        const float* __restrict__ gw1, const float* __restrict__ gb1,
        const float* __restrict__ gw2, const float* __restrict__ gb2) {
    int w    = threadIdx.x >> 6;       // wave 0..3
    int lane = threadIdx.x & 63;
    int s = blockIdx.x & 7;
    int i = (blockIdx.x >> 3) * 4 + w;
    int r = s * Nn + i;

    __shared__ float2 pn[4][MAXDEG];   // per-wave (p, j) slab

    int d = deg[r]; if (d > MAXDEG) d = MAXDEG;

    // ---- softmax over neighbor list (this wave, 64 lanes) ----
    float a1 = ah1r[r];
    const int* al = adj + (size_t)r * MAXDEG;
    const float* ah2s = ah2r + (size_t)s * Nn;
    int jlo = 0, jhi = 0;
    float elo = -INFINITY, ehi = -INFINITY;
    if (lane < d) {
        jlo = al[lane];
        float e = a1 + ah2s[jlo];
        elo = e > 0.f ? e : 0.2f * e;              // leaky_relu(0.2)
    }
    if (lane + 64 < d) {
        jhi = al[lane + 64];
        float e = a1 + ah2s[jhi];
        ehi = e > 0.f ? e : 0.2f * e;
    }
    float m = fmaxf(elo, ehi);
    #pragma unroll
    for (int o = 32; o > 0; o >>= 1) m = fmaxf(m, __shfl_xor(m, o));
    float exlo = (lane < d)      ? __expf(elo - m) : 0.f;
    float exhi = (lane + 64 < d) ? __expf(ehi - m) : 0.f;
    float sum = exlo + exhi;
    #pragma unroll
    for (int o = 32; o > 0; o >>= 1) sum += __shfl_xor(sum, o);
    float inv = (d > 0) ? 1.0f / sum : 0.f;

    // publish (p, j) — all 128 entries written (zero-padded past d)
    pn[w][lane]      = make_float2(exlo, __int_as_float(jlo));
    pn[w][lane + 64] = make_float2(exhi, __int_as_float(jhi));
    // no __syncthreads: same-wave LDS write->read, compiler emits lgkmcnt

    // ---- sparse aggregate: group g = lane>>4 handles neighbors k = 4t+g;
    //      lane f = lane&15 owns features 8f..8f+7 (one uint4 of fp16) ----
    const uint4* xwu = (const uint4*)(xwh + (size_t)s * Nn * Dn);  // 16/row
    int g = lane >> 4;
    int f = lane & 15;
    __half2 acc2[4];
    #pragma unroll
    for (int e = 0; e < 4; ++e) acc2[e] = __halves2half2(__float2half(0.f), __float2half(0.f));
    int dpad = (d + 15) & ~15;
    for (int base = 0; base < dpad; base += 16) {
        float2 q[4];
        uint4  v[4];
        #pragma unroll
        for (int t = 0; t < 4; ++t) q[t] = pn[w][base + 4 * t + g];
        #pragma unroll
        for (int t = 0; t < 4; ++t)
            v[t] = xwu[(size_t)__float_as_int(q[t].y) * 16 + f];
        #pragma unroll
        for (int t = 0; t < 4; ++t) {
            __half   ph = __float2half(q[t].x);
            __half2  p2 = __halves2half2(ph, ph);
            const __half2* hh = (const __half2*)&v[t];
            acc2[0] = __hfma2(p2, hh[0], acc2[0]);
            acc2[1] = __hfma2(p2, hh[1], acc2[1]);
            acc2[2] = __hfma2(p2, hh[2], acc2[2]);
            acc2[3] = __hfma2(p2, hh[3], acc2[3]);
        }
    }
    // convert to fp32, then fold the 4 groups across lanes
    float2 f0 = __half22float2(acc2[0]);
    float2 f1 = __half22float2(acc2[1]);
    float2 f2 = __half22float2(acc2[2]);
    float2 f3 = __half22float2(acc2[3]);
    float accA[4] = { f0.x, f0.y, f1.x, f1.y };
    float accB[4] = { f2.x, f2.y, f3.x, f3.y };
    #pragma unroll
    for (int e = 0; e < 4; ++e) {
        accA[e] += __shfl_xor(accA[e], 16);
        accA[e] += __shfl_xor(accA[e], 32);
        accB[e] += __shfl_xor(accB[e], 16);
        accB[e] += __shfl_xor(accB[e], 32);
    }

    // ---- residual + ELU + store (fp32 + fp16 mirror) + next-iter ah ----
    if (lane < 16) {
        float4* x4 = (float4*)(x + (size_t)r * Dn);
        float4 vA4 = x4[2 * lane], vB4 = x4[2 * lane + 1];
        float4 tA, tB, rA, rB;
        tA.x = vA4.x + accA[0] * inv;  tA.y = vA4.y + accA[1] * inv;
        tA.z = vA4.z + accA[2] * inv;  tA.w = vA4.w + accA[3] * inv;
        tB.x = vB4.x + accB[0] * inv;  tB.y = vB4.y + accB[1] * inv;
        tB.z = vB4.z + accB[2] * inv;  tB.w = vB4.w + accB[3] * inv;
        rA.x = tA.x > 0.f ? tA.x : (expf(tA.x) - 1.f);
        rA.y = tA.y > 0.f ? tA.y : (expf(tA.y) - 1.f);
        rA.z = tA.z > 0.f ? tA.z : (expf(tA.z) - 1.f);
        rA.w = tA.w > 0.f ? tA.w : (expf(tA.w) - 1.f);
        rB.x = tB.x > 0.f ? tB.x : (expf(tB.x) - 1.f);
        rB.y = tB.y > 0.f ? tB.y : (expf(tB.y) - 1.f);
        rB.z = tB.z > 0.f ? tB.z : (expf(tB.z) - 1.f);
        rB.w = tB.w > 0.f ? tB.w : (expf(tB.w) - 1.f);
        x4[2 * lane]     = rA;
        x4[2 * lane + 1] = rB;

        // fp16 mirror for the next MFMA gemm
        __half2 h0 = __floats2half2_rn(rA.x, rA.y);
        __half2 h1 = __floats2half2_rn(rA.z, rA.w);
        __half2 h2 = __floats2half2_rn(rB.x, rB.y);
        __half2 h3 = __floats2half2_rn(rB.z, rB.w);
        uint4 u;
        u.x = *(unsigned*)&h0; u.y = *(unsigned*)&h1;
        u.z = *(unsigned*)&h2; u.w = *(unsigned*)&h3;
        ((uint4*)(xh + (size_t)r * Dn))[lane] = u;

        // ah for next iteration (row is in rA/rB across lanes 0..15)
        const float4* w14 = (const float4*)gw1;
        const float4* w24 = (const float4*)gw2;
        float4 wa = w14[2 * lane], wb = w14[2 * lane + 1];
        float4 ua = w24[2 * lane], ub = w24[2 * lane + 1];
        float p1 = rA.x * wa.x + rA.y * wa.y + rA.z * wa.z + rA.w * wa.w
                 + rB.x * wb.x + rB.y * wb.y + rB.z * wb.z + rB.w * wb.w;
        float p2 = rA.x * ua.x + rA.y * ua.y + rA.z * ua.z + rA.w * ua.w
                 + rB.x * ub.x + rB.y * ub.y + rB.z * ub.z + rB.w * ub.w;
        #pragma unroll
        for (int o = 8; o >= 1; o >>= 1) {
            p1 += __shfl_xor(p1, o);
            p2 += __shfl_xor(p2, o);
        }
        if (lane == 0) {
            ah1w[r] = p1 + gb1[0];
            ah2w[r] = p2 + gb2[0];
        }
    }
}

// ---------------------------------------------------------------------------
// Stage-1 reduction over rows: 32 chunks of 64 rows per batch, fwd+rev fused.
__global__ void reduce_partial(const float* __restrict__ x, float* __restrict__ part) {
    int b = blockIdx.x >> 5;
    int c = blockIdx.x & 31;
    int tid = threadIdx.x;                     // 0..127 = d
    const float* xf = x + ((size_t)(b * Nn) + c * 64) * Dn;
    const float* xr = x + ((size_t)((4 + b) * Nn) + c * 64) * Dn;
    float sv = 0.f;
    for (int i = 0; i < 64; ++i)
        sv += xf[(size_t)i * Dn + tid] + xr[(size_t)i * Dn + tid];
    part[(size_t)blockIdx.x * Dn + tid] = sv;
}

// ---------------------------------------------------------------------------
// Stage-2: mid[b] = sum of partials; out[b] = mid @ Wout + bout
__global__ void final_out(const float* __restrict__ part,
                          const float* __restrict__ Wout, const float* __restrict__ bout,
                          float* __restrict__ out) {
    int b = blockIdx.x;
    int tid = threadIdx.x;                     // 128 threads
    __shared__ float mid[Dn];
    float sv = 0.f;
    for (int c = 0; c < 32; ++c) sv += part[(size_t)(b * 32 + c) * Dn + tid];
    mid[tid] = sv;
    __syncthreads();
    if (tid < OUTn) {
        float o = bout[tid];
        #pragma unroll 4
        for (int k = 0; k < Dn; ++k) o = fmaf(mid[k], Wout[k * OUTn + tid], o);
        out[b * OUTn + tid] = o;
    }
}

// ---------------------------------------------------------------------------
extern "C" void kernel_launch(void* const* d_in, const int* in_sizes, int n_in,
                              void* d_out, int out_size, void* d_ws, size_t ws_size,
                              hipStream_t stream) {
    const float* INPUT = (const float*)d_in[0];
    const float* CFG   = (const float*)d_in[1];
    // d_in[2] = LFG, unused by the forward pass
    const float* w1    = (const float*)d_in[3];
    const float* b1    = (const float*)d_in[4];
    const float* w2    = (const float*)d_in[5];
    const float* b2    = (const float*)d_in[6];
    const float* Wm    = (const float*)d_in[7];
    const float* Wout  = (const float*)d_in[8];
    const float* bout  = (const float*)d_in[9];
    float* out = (float*)d_out;

    // workspace layout (~26.7 MB)
    float*  x    = (float*)d_ws;                          // Sn*Nn*Dn   (8 MB)
    __half* xwh  = (__half*)(x + (size_t)Sn * Nn * Dn);   // Sn*Nn*Dn   (4 MB)
    __half* xh   = xwh + (size_t)Sn * Nn * Dn;            // Sn*Nn*Dn   (4 MB)
    __half* WhT  = xh + (size_t)Sn * Nn * Dn;             // Dn*Dn      (32 KB)
    int*    adj  = (int*)(WhT + (size_t)Dn * Dn);         // Sn*Nn*MAXDEG (8 MB)
    int*    deg  = adj + (size_t)Sn * Nn * MAXDEG;        // Sn*Nn
    float*  ah1a = (float*)(deg + Sn * Nn);               // Sn*Nn
    float*  ah2a = ah1a + Sn * Nn;                        // Sn*Nn
    float*  ah1b = ah2a + Sn * Nn;                        // Sn*Nn
    float*  ah2b = ah1b + Sn * Nn;                        // Sn*Nn
    float*  part = ah2b + Sn * Nn;                        // Bn*32*Dn
    unsigned long long* bits = (unsigned long long*)(part + Bn * 32 * Dn); // 2 MB

    fwd_bits_init<<<(Bn * Nn) / 4 + (Bn * Nn) / 8 + 1, 256, 0, stream>>>(
        (const float4*)CFG, bits, adj, deg, (const float4*)INPUT, (float4*)x,
        xh, Wm, WhT, w1, b1, w2, b2, ah1a, ah2a);

    for (int it = 0; it < NITER; ++it) {
        if (it == 0) {
            gemm_rev<<<4096, 256, 0, stream>>>(xh, WhT, xwh, bits, adj, deg);
        } else {
            gemm_mfma<<<2048, 256, 0, stream>>>(xh, WhT, xwh);
        }
        const float* r1 = (it & 1) ? ah1b : ah1a;
        const float* r2 = (it & 1) ? ah2b : ah2a;
        float* w1p = (it & 1) ? ah1a : ah1b;
        float* w2p = (it & 1) ? ah2a : ah2b;
        attn_agg<<<(Sn * Nn) / 4, 256, 0, stream>>>(
            x, xh, xwh, adj, deg, r1, r2, w1p, w2p, w1, b1, w2, b2);
    }

    reduce_partial<<<Bn * 32, 128, 0, stream>>>(x, part);
    final_out     <<<Bn, 128, 0, stream>>>(part, Wout, bout, out);
}